// Round 7
// baseline (1759.562 us; speedup 1.0000x reference)
//
#include <hip/hip_runtime.h>
#include <hip/hip_bf16.h>

#define N_NODES 50000
#define N_EDGES 600000
#define NODE_IN 32
#define EDGE_IN 16
#define HID 128
#define NLAYER 3
#define GCTX 64

typedef _Float16 h2 __attribute__((ext_vector_type(2)));
typedef _Float16 f16x8 __attribute__((ext_vector_type(8)));
typedef float f32x4 __attribute__((ext_vector_type(4)));

__device__ __forceinline__ float bf2f(unsigned short u) {
  union { unsigned int i; float f; } c; c.i = ((unsigned int)u) << 16; return c.f;
}
__device__ __forceinline__ unsigned int bfp2hp(unsigned int b) {
  union { unsigned int i; float f; } lo, hi;
  lo.i = b << 16; hi.i = b & 0xffff0000u;
  h2 r; r.x = (_Float16)lo.f; r.y = (_Float16)hi.f;
  union { h2 h; unsigned int u; } c; c.h = r; return c.u;
}
__device__ __forceinline__ h2 u2h2(unsigned int u) {
  union { unsigned int u; h2 h; } c; c.u = u; return c.h;
}
__device__ __forceinline__ float dot2(h2 a, h2 b, float c) {
#if __has_builtin(__builtin_amdgcn_fdot2)
  return __builtin_amdgcn_fdot2(a, b, c, false);
#else
  return c + (float)a.x * (float)b.x + (float)a.y * (float)b.y;
#endif
}

// generic loaders: fm 0=bf16, 1=fp32, 2=fp16
__device__ __forceinline__ unsigned int load_pair(const void* p, size_t pairIdx, int fm) {
  if (fm == 0) return bfp2hp(((const unsigned int*)p)[pairIdx]);
  if (fm == 2) return ((const unsigned int*)p)[pairIdx];
  const float* f = (const float*)p;
  h2 r; r.x = (_Float16)f[2 * pairIdx]; r.y = (_Float16)f[2 * pairIdx + 1];
  union { h2 h; unsigned int u; } c; c.h = r; return c.u;
}
__device__ __forceinline__ float load_scal(const void* p, size_t idx, int fm) {
  if (fm == 0) return bf2f(((const unsigned short*)p)[idx]);
  if (fm == 2) return (float)((const _Float16*)p)[idx];
  return ((const float*)p)[idx];
}
__device__ __forceinline__ int load_idx(const void* p, size_t pos, int im) {
  if (im == 0) return ((const int*)p)[pos];
  return (int)((const long long*)p)[pos];
}
__device__ __forceinline__ uint4 zero4() { uint4 z; z.x = z.y = z.z = z.w = 0u; return z; }
__device__ __forceinline__ uint4 load8(const void* p, size_t eoff, int fm) {
  uint4 r;
  if (fm == 0) {
    uint4 t = *(const uint4*)((const unsigned short*)p + eoff);
    r.x = bfp2hp(t.x); r.y = bfp2hp(t.y); r.z = bfp2hp(t.z); r.w = bfp2hp(t.w);
  } else if (fm == 2) {
    r = *(const uint4*)((const unsigned short*)p + eoff);
  } else {
    const float* f = (const float*)p + eoff;
    h2 a, b, c, d;
    a.x = (_Float16)f[0]; a.y = (_Float16)f[1];
    b.x = (_Float16)f[2]; b.y = (_Float16)f[3];
    c.x = (_Float16)f[4]; c.y = (_Float16)f[5];
    d.x = (_Float16)f[6]; d.y = (_Float16)f[7];
    union { h2 h; unsigned int u; } ua, ub, uc, ud;
    ua.h = a; ub.h = b; uc.h = c; ud.h = d;
    r.x = ua.u; r.y = ub.u; r.z = uc.u; r.w = ud.u;
  }
  return r;
}
__device__ __forceinline__ f32x4 mfma16(uint4 a, uint4 b, f32x4 c) {
  union { uint4 u; f16x8 h; } A, B; A.u = a; B.u = b;
  return __builtin_amdgcn_mfma_f32_16x16x32_f16(A.h, B.h, c, 0, 0, 0);
}

__device__ __forceinline__ float wave_sum(float v) {
  for (int m = 32; m >= 1; m >>= 1) v += __shfl_xor(v, m, 64);
  return v;
}
__device__ __forceinline__ float wave_max(float v) {
  for (int m = 32; m >= 1; m >>= 1) v = fmaxf(v, __shfl_xor(v, m, 64));
  return v;
}

// ---------------- dtype detector -------------------------------------------
__global__ __launch_bounds__(256) void k_detect(const unsigned int* __restrict__ x,
                                                const unsigned int* __restrict__ ei,
                                                int* __restrict__ flags) {
  __shared__ int sIn, sOddNZ;
  const int tid = threadIdx.x;
  if (tid == 0) { sIn = 0; sOddNZ = 0; }
  __syncthreads();
  int cnt = 0;
  for (int i = tid; i < 2048; i += 256) {
    unsigned int d = x[i];
    float v0 = fabsf(bf2f((unsigned short)(d & 0xffff)));
    float v1 = fabsf(bf2f((unsigned short)(d >> 16)));
    if (v0 >= 0.1f && v0 <= 6.0f) cnt++;
    if (v1 >= 0.1f && v1 <= 6.0f) cnt++;
  }
  int nz = 0;
  for (int i = tid; i < 512; i += 256)
    if (ei[2 * i + 1] != 0) nz++;
  atomicAdd(&sIn, cnt);
  atomicAdd(&sOddNZ, nz);
  __syncthreads();
  if (tid == 0) {
    float frac = (float)sIn / 4096.f;
    flags[0] = (frac > 0.75f) ? 0 : ((frac >= 0.3f) ? 1 : 2);
    flags[1] = (sOddNZ < 4) ? 1 : 0;  // 1 => int64 edge_index
  }
}

// ---------------- node projection ------------------------------------------
__global__ __launch_bounds__(256) void k_proj(
    const void* __restrict__ x, const void* __restrict__ W,
    const void* __restrict__ b, _Float16* __restrict__ h,
    const int* __restrict__ flags) {
  const int fm = flags[0];
  const int tid = threadIdx.x;
  const int slot = tid >> 7;
  const int t = tid & 127;
  __shared__ __align__(16) _Float16 sX[2][NODE_IN];
  unsigned int w[16];
#pragma unroll
  for (int i = 0; i < 16; ++i) w[i] = load_pair(W, (size_t)t * 16 + i, fm);
  const float bias = load_scal(b, t, fm);
  unsigned int* sx32 = (unsigned int*)sX[slot];
  for (int base = blockIdx.x * 2; base < N_NODES; base += gridDim.x * 2) {
    const int n = base + slot;
    if (t < 16) sx32[t] = load_pair(x, (size_t)n * 16 + t, fm);
    __syncthreads();
    float a0 = bias, a1 = 0.f, a2 = 0.f, a3 = 0.f;
    const uint4* vq = (const uint4*)sx32;
#pragma unroll
    for (int q = 0; q < 4; ++q) {
      uint4 v = vq[q];
      a0 = dot2(u2h2(v.x), u2h2(w[q * 4 + 0]), a0);
      a1 = dot2(u2h2(v.y), u2h2(w[q * 4 + 1]), a1);
      a2 = dot2(u2h2(v.z), u2h2(w[q * 4 + 2]), a2);
      a3 = dot2(u2h2(v.w), u2h2(w[q * 4 + 3]), a3);
    }
    h[(size_t)n * HID + t] = (_Float16)fmaxf((a0 + a1) + (a2 + a3), 0.f);
    __syncthreads();
  }
}

// ---------------- CSR build --------------------------------------------------
__global__ __launch_bounds__(256) void k_hist(const void* __restrict__ ei,
                                              int* __restrict__ cnt,
                                              const int* __restrict__ flags) {
  const int im = flags[1];
  for (int e = blockIdx.x * 256 + threadIdx.x; e < N_EDGES; e += gridDim.x * 256)
    atomicAdd(&cnt[load_idx(ei, N_EDGES + e, im)], 1);
}
__global__ __launch_bounds__(256) void k_scan(const int* __restrict__ cnt,
                                              int* __restrict__ row_ptr,
                                              int* __restrict__ cur) {
  __shared__ int sPart[256];
  const int t = threadIdx.x;
  const int c0 = t * 196;
  const int c1 = (c0 + 196 < N_NODES) ? c0 + 196 : N_NODES;
  int s = 0;
  for (int i = c0; i < c1; ++i) s += cnt[i];
  sPart[t] = s;
  __syncthreads();
  if (t == 0) {
    int run = 0;
    for (int i = 0; i < 256; ++i) { int v = sPart[i]; sPart[i] = run; run += v; }
    row_ptr[N_NODES] = run;
  }
  __syncthreads();
  int off = sPart[t];
  for (int i = c0; i < c1; ++i) {
    row_ptr[i] = off; cur[i] = off; off += cnt[i];
  }
}
// scatter: pos<-edge; also pack (src,dst) and permuted fp16 edge_attr
__global__ __launch_bounds__(256) void k_scatter(const void* __restrict__ ei,
                                                 const void* __restrict__ ea,
                                                 int* __restrict__ cur,
                                                 int2* __restrict__ sd2,
                                                 _Float16* __restrict__ eaPerm,
                                                 const int* __restrict__ flags) {
  const int im = flags[1], fm = flags[0];
  for (int e = blockIdx.x * 256 + threadIdx.x; e < N_EDGES; e += gridDim.x * 256) {
    const int s = load_idx(ei, e, im);
    const int d = load_idx(ei, N_EDGES + e, im);
    const int pos = atomicAdd(&cur[d], 1);
    int2 sd; sd.x = s; sd.y = d;
    sd2[pos] = sd;
    uint4 lo = load8(ea, (size_t)e * 16, fm);
    uint4 hi = load8(ea, (size_t)e * 16 + 8, fm);
    *(uint4*)(eaPerm + (size_t)pos * 16) = lo;
    *(uint4*)(eaPerm + (size_t)pos * 16 + 8) = hi;
  }
}

// ================= MFMA fused edge kernel, CSR order, 32-edge tiles ==========
#define SAP 296
#define SM1P 136
#define NT32 (N_EDGES / 32)

__global__ __launch_bounds__(256) void k_edge(
    const _Float16* __restrict__ h, const int2* __restrict__ sd2,
    const _Float16* __restrict__ eaPerm,
    const void* __restrict__ aw1, const void* __restrict__ ab1,
    const void* __restrict__ aw2, const void* __restrict__ ab2,
    const void* __restrict__ mw1, const void* __restrict__ mb1,
    const void* __restrict__ mw2, const void* __restrict__ mb2,
    float* __restrict__ scores, float* __restrict__ pmax,
    _Float16* __restrict__ msgbuf, const int* __restrict__ flags, int lay) {
  const int fm = flags[0];
  const int tid = threadIdx.x;
  const int w = tid >> 6, l = tid & 63;
  const int m16 = l & 15, q = l >> 4;
  __shared__ __align__(16) _Float16 sA[2][32 * SAP];
  __shared__ __align__(16) _Float16 sM1[2][32 * SM1P];
  __shared__ float sS[2][4][32];

  // ---- weight fragments (resident in registers) ----
  uint4 bA[9], bM1[2][5], bM2[2][4];
  {
    const int arow = w * 16 + m16;
    const size_t awb = (size_t)lay * 64 * 272 + (size_t)arow * 272;
#pragma unroll
    for (int ks = 0; ks < 9; ++ks) {
      const int c0 = ks * 32 + q * 8;
      bA[ks] = (c0 < 272) ? load8(aw1, awb + c0, fm) : zero4();
    }
#pragma unroll
    for (int nt = 0; nt < 2; ++nt) {
      const int mrow = (2 * w + nt) * 16 + m16;
      const size_t m1b = (size_t)lay * 128 * 144 + (size_t)mrow * 144;
#pragma unroll
      for (int ks = 0; ks < 5; ++ks) {
        const int c0 = ks * 32 + q * 8;
        bM1[nt][ks] = (c0 < 144) ? load8(mw1, m1b + c0, fm) : zero4();
      }
      const size_t m2b = (size_t)lay * 128 * 128 + (size_t)mrow * 128;
#pragma unroll
      for (int ks = 0; ks < 4; ++ks)
        bM2[nt][ks] = load8(mw2, m2b + ks * 32 + q * 8, fm);
    }
  }
  const float ab1v = load_scal(ab1, lay * 64 + w * 16 + m16, fm);
  const float w2s  = load_scal(aw2, lay * 64 + w * 16 + m16, fm);
  const float b2f  = load_scal(ab2, lay, fm);
  float b1v[2], b2v[2];
#pragma unroll
  for (int nt = 0; nt < 2; ++nt) {
    b1v[nt] = load_scal(mb1, lay * 128 + (2 * w + nt) * 16 + m16, fm);
    b2v[nt] = load_scal(mb2, lay * 128 + (2 * w + nt) * 16 + m16, fm);
  }

  const int ide0 = tid >> 4, ch = tid & 15, ide1 = ide0 + 16;
  float lmax = -3.4e38f;
  uint4 rHs0, rHd0, rHs1, rHd1, rEa;
  const int G = gridDim.x;
  int t = blockIdx.x, pt = -1, buf = 0;

  // zero the ea padding [272:288) of both buffers once
  if (tid < 128) {
    const int b = tid >> 6, s = tid & 63;
    *(uint4*)(sA[b] + (s >> 1) * SAP + 272 + (s & 1) * 8) = zero4();
  }
  {  // prologue prefetch
    const int e0 = t * 32;
    const int2 s0 = sd2[e0 + ide0], s1 = sd2[e0 + ide1];
    rHs0 = *(const uint4*)(h + (size_t)s0.x * HID + ch * 8);
    rHd0 = *(const uint4*)(h + (size_t)s0.y * HID + ch * 8);
    rHs1 = *(const uint4*)(h + (size_t)s1.x * HID + ch * 8);
    rHd1 = *(const uint4*)(h + (size_t)s1.y * HID + ch * 8);
    if (tid < 64)
      rEa = *(const uint4*)(eaPerm + (size_t)(e0 + (tid >> 1)) * 16 + (tid & 1) * 8);
  }
  __syncthreads();  // pad zeros visible

  while (t < NT32) {
    _Float16* A = sA[buf];
    *(uint4*)(A + ide0 * SAP + ch * 8) = rHs0;
    *(uint4*)(A + ide0 * SAP + 128 + ch * 8) = rHd0;
    *(uint4*)(A + ide1 * SAP + ch * 8) = rHs1;
    *(uint4*)(A + ide1 * SAP + 128 + ch * 8) = rHd1;
    if (tid < 64)
      *(uint4*)(A + (tid >> 1) * SAP + 256 + (tid & 1) * 8) = rEa;
    __syncthreads();
    const int nxt = t + G;
    if (nxt < NT32) {  // prefetch next tile (overlaps MFMA below)
      const int e0 = nxt * 32;
      const int2 s0 = sd2[e0 + ide0], s1 = sd2[e0 + ide1];
      rHs0 = *(const uint4*)(h + (size_t)s0.x * HID + ch * 8);
      rHd0 = *(const uint4*)(h + (size_t)s0.y * HID + ch * 8);
      rHs1 = *(const uint4*)(h + (size_t)s1.x * HID + ch * 8);
      rHd1 = *(const uint4*)(h + (size_t)s1.y * HID + ch * 8);
      if (tid < 64)
        rEa = *(const uint4*)(eaPerm + (size_t)(e0 + (tid >> 1)) * 16 + (tid & 1) * 8);
    }
    // ---- phase 1 (tile t), two m-groups of 16 edges ----
#pragma unroll
    for (int mg = 0; mg < 2; ++mg) {
      const int arow = m16 + 16 * mg;
      uint4 aF[9];
#pragma unroll
      for (int ks = 0; ks < 9; ++ks)
        aF[ks] = *(const uint4*)(A + arow * SAP + ks * 32 + q * 8);
      {
        f32x4 aacc = {0.f, 0.f, 0.f, 0.f};
#pragma unroll
        for (int ks = 0; ks < 9; ++ks) aacc = mfma16(aF[ks], bA[ks], aacc);
        float sv[4];
#pragma unroll
        for (int r = 0; r < 4; ++r) {
          float v = aacc[r] + ab1v;
          v = (v > 0.f) ? v : 0.2f * v;  // leaky_relu(0.2)
          sv[r] = v * w2s;
        }
#pragma unroll
        for (int mk = 1; mk <= 8; mk <<= 1) {
#pragma unroll
          for (int r = 0; r < 4; ++r) sv[r] += __shfl_xor(sv[r], mk, 64);
        }
        if (m16 == 0)
          *(float4*)(&sS[buf][w][mg * 16 + q * 4]) = make_float4(sv[0], sv[1], sv[2], sv[3]);
      }
#pragma unroll
      for (int nt = 0; nt < 2; ++nt) {
        f32x4 macc = {0.f, 0.f, 0.f, 0.f};
#pragma unroll
        for (int ks = 0; ks < 4; ++ks) macc = mfma16(aF[ks], bM1[nt][ks], macc);
        macc = mfma16(aF[8], bM1[nt][4], macc);
        const int col = (2 * w + nt) * 16 + m16;
#pragma unroll
        for (int r = 0; r < 4; ++r)
          sM1[buf][(mg * 16 + q * 4 + r) * SM1P + col] = (_Float16)fmaxf(macc[r] + b1v[nt], 0.f);
      }
    }
    // ---- phase 2 (tile pt) ----
    if (pt >= 0) {
      const _Float16* M1 = sM1[buf ^ 1];
#pragma unroll
      for (int mg = 0; mg < 2; ++mg) {
        uint4 a2F[4];
#pragma unroll
        for (int ks = 0; ks < 4; ++ks)
          a2F[ks] = *(const uint4*)(M1 + (m16 + 16 * mg) * SM1P + ks * 32 + q * 8);
#pragma unroll
        for (int nt = 0; nt < 2; ++nt) {
          f32x4 oacc = {0.f, 0.f, 0.f, 0.f};
#pragma unroll
          for (int ks = 0; ks < 4; ++ks) oacc = mfma16(a2F[ks], bM2[nt][ks], oacc);
          const int col = (2 * w + nt) * 16 + m16;
#pragma unroll
          for (int r = 0; r < 4; ++r)
            msgbuf[(size_t)(pt * 32 + mg * 16 + q * 4 + r) * HID + col] =
                (_Float16)(oacc[r] + b2v[nt]);
        }
      }
      if (tid < 32) {
        const float s = sS[buf ^ 1][0][tid] + sS[buf ^ 1][1][tid] +
                        sS[buf ^ 1][2][tid] + sS[buf ^ 1][3][tid] + b2f;
        scores[pt * 32 + tid] = s;
        lmax = fmaxf(lmax, s);
      }
    }
    pt = t; t = nxt; buf ^= 1;
  }
  __syncthreads();
  if (pt >= 0) {  // epilogue phase 2
    const _Float16* M1 = sM1[buf ^ 1];
#pragma unroll
    for (int mg = 0; mg < 2; ++mg) {
      uint4 a2F[4];
#pragma unroll
      for (int ks = 0; ks < 4; ++ks)
        a2F[ks] = *(const uint4*)(M1 + (m16 + 16 * mg) * SM1P + ks * 32 + q * 8);
#pragma unroll
      for (int nt = 0; nt < 2; ++nt) {
        f32x4 oacc = {0.f, 0.f, 0.f, 0.f};
#pragma unroll
        for (int ks = 0; ks < 4; ++ks) oacc = mfma16(a2F[ks], bM2[nt][ks], oacc);
        const int col = (2 * w + nt) * 16 + m16;
#pragma unroll
        for (int r = 0; r < 4; ++r)
          msgbuf[(size_t)(pt * 32 + mg * 16 + q * 4 + r) * HID + col] =
              (_Float16)(oacc[r] + b2v[nt]);
      }
    }
    if (tid < 32) {
      const float s = sS[buf ^ 1][0][tid] + sS[buf ^ 1][1][tid] +
                      sS[buf ^ 1][2][tid] + sS[buf ^ 1][3][tid] + b2f;
      scores[pt * 32 + tid] = s;
      lmax = fmaxf(lmax, s);
    }
  }
  if (w == 0) {
    float m = wave_max((l < 32) ? lmax : -3.4e38f);
    if (tid == 0) pmax[blockIdx.x] = m;
  }
}

// ---------------- global max reduce -----------------------------------------
__global__ __launch_bounds__(256) void k_rmax(const float* __restrict__ pmax, int n,
                                              float* __restrict__ gmax) {
  float m = -3.4e38f;
  for (int i = threadIdx.x; i < n; i += 256) m = fmaxf(m, pmax[i]);
  m = wave_max(m);
  __shared__ float sm[4];
  if ((threadIdx.x & 63) == 0) sm[threadIdx.x >> 6] = m;
  __syncthreads();
  if (threadIdx.x == 0) gmax[0] = fmaxf(fmaxf(sm[0], sm[1]), fmaxf(sm[2], sm[3]));
}

// ============ fused softmax-gather + update MLP + residual + LN ==============
// gather = column-parallel streaming walk: 128 threads own one column each,
// each 128-thread half walks 8 nodes' contiguous CSR edge range row-by-row.
#define SUP 264
#define SOP 132
__global__ __launch_bounds__(256) void k_gupd(
    _Float16* __restrict__ h, const _Float16* __restrict__ msgbuf,
    const float* __restrict__ scores, const int* __restrict__ row_ptr,
    const float* __restrict__ gmax,
    const void* __restrict__ uw1, const void* __restrict__ ub1,
    const void* __restrict__ uw2, const void* __restrict__ ub2,
    const void* __restrict__ lng, const void* __restrict__ lnb,
    const int* __restrict__ flags, int lay) {
  const int fm = flags[0];
  const int tid = threadIdx.x;
  const int w = tid >> 6, l = tid & 63;
  const int m16 = l & 15, q = l >> 4;
  __shared__ __align__(16) _Float16 sU[16 * SUP];
  __shared__ __align__(16) _Float16 sM1[16 * SM1P];
  __shared__ __align__(16) float sO[16 * SOP];

  uint4 bU1[2][8], bU2[2][4];
  float b1v[2], b2v[2];
#pragma unroll
  for (int nt = 0; nt < 2; ++nt) {
    const int row = w * 32 + nt * 16 + m16;
    const size_t b1p = (size_t)lay * 128 * 256 + (size_t)row * 256;
#pragma unroll
    for (int ks = 0; ks < 8; ++ks) bU1[nt][ks] = load8(uw1, b1p + ks * 32 + q * 8, fm);
    const size_t b2p = (size_t)lay * 128 * 128 + (size_t)row * 128;
#pragma unroll
    for (int ks = 0; ks < 4; ++ks) bU2[nt][ks] = load8(uw2, b2p + ks * 32 + q * 8, fm);
    b1v[nt] = load_scal(ub1, lay * 128 + row, fm);
    b2v[nt] = load_scal(ub2, lay * 128 + row, fm);
  }
  const int nd = tid >> 4, sc = tid & 15;
  float g8[8], be8[8];
#pragma unroll
  for (int j = 0; j < 8; ++j) {
    g8[j] = load_scal(lng, lay * 128 + sc * 8 + j, fm);
    be8[j] = load_scal(lnb, lay * 128 + sc * 8 + j, fm);
  }
  const float M = gmax[0];
  const int half = tid >> 7, col = tid & 127;

  for (int n0 = blockIdx.x * 16; n0 < N_NODES; n0 += gridDim.x * 16) {
    // ---- phase 0: streaming softmax-weighted aggregation into sU ----
    {
      int n = n0 + half * 8;
      const int nStop = n + 8;
      int p = row_ptr[n];
      const int pEnd = row_ptr[nStop];
      int nb = row_ptr[n + 1];
      float acc = 0.f, den = 0.f;
      for (; p < pEnd; ++p) {
        while (p == nb) {  // flush completed node (handles empty nodes)
          sU[(n - n0) * SUP + 128 + col] = (_Float16)(acc / (den + 1e-6f));
          acc = 0.f; den = 0.f; ++n; nb = row_ptr[n + 1];
        }
        const float wgt = __expf(scores[p] - M);
        acc += wgt * (float)msgbuf[(size_t)p * HID + col];
        den += wgt;
      }
      while (n < nStop) {  // trailing flush
        sU[(n - n0) * SUP + 128 + col] = (_Float16)(acc / (den + 1e-6f));
        acc = 0.f; den = 0.f; ++n;
      }
    }
    {  // stage h rows (residual + MLP input)
      const int nn = 4 * w + (l >> 4), chk = l & 15;
      *(uint4*)(sU + nn * SUP + chk * 8) =
          *(const uint4*)(h + (size_t)(n0 + nn) * HID + chk * 8);
    }
    __syncthreads();
    // ---- phase 1: u = relu([h|agg] @ uw1^T + b1) ----
    uint4 aF[8];
#pragma unroll
    for (int ks = 0; ks < 8; ++ks)
      aF[ks] = *(const uint4*)(sU + m16 * SUP + ks * 32 + q * 8);
#pragma unroll
    for (int nt = 0; nt < 2; ++nt) {
      f32x4 acc = {0.f, 0.f, 0.f, 0.f};
#pragma unroll
      for (int ks = 0; ks < 8; ++ks) acc = mfma16(aF[ks], bU1[nt][ks], acc);
      const int colw = w * 32 + nt * 16 + m16;
#pragma unroll
      for (int r = 0; r < 4; ++r)
        sM1[(q * 4 + r) * SM1P + colw] = (_Float16)fmaxf(acc[r] + b1v[nt], 0.f);
    }
    __syncthreads();
    // ---- phase 2: out = u @ uw2^T + b2; r = relu(out + h) ----
    uint4 a2F[4];
#pragma unroll
    for (int ks = 0; ks < 4; ++ks)
      a2F[ks] = *(const uint4*)(sM1 + m16 * SM1P + ks * 32 + q * 8);
#pragma unroll
    for (int nt = 0; nt < 2; ++nt) {
      f32x4 acc = {0.f, 0.f, 0.f, 0.f};
#pragma unroll
      for (int ks = 0; ks < 4; ++ks) acc = mfma16(a2F[ks], bU2[nt][ks], acc);
      const int colw = w * 32 + nt * 16 + m16;
#pragma unroll
      for (int r = 0; r < 4; ++r) {
        const int row = q * 4 + r;
        const float hres = (float)sU[row * SUP + colw];
        sO[row * SOP + colw] = fmaxf(acc[r] + b2v[nt] + hres, 0.f);
      }
    }
    __syncthreads();
    // ---- layernorm: 16 threads per node ----
    float v[8], s1 = 0.f, s2 = 0.f;
    const float4 p0 = *(const float4*)(sO + nd * SOP + sc * 8);
    const float4 p1 = *(const float4*)(sO + nd * SOP + sc * 8 + 4);
    v[0] = p0.x; v[1] = p0.y; v[2] = p0.z; v[3] = p0.w;
    v[4] = p1.x; v[5] = p1.y; v[6] = p1.z; v[7] = p1.w;
#pragma unroll
    for (int j = 0; j < 8; ++j) { s1 += v[j]; s2 += v[j] * v[j]; }
#pragma unroll
    for (int mk = 1; mk <= 8; mk <<= 1) {
      s1 += __shfl_xor(s1, mk, 64);
      s2 += __shfl_xor(s2, mk, 64);
    }
    const float mu = s1 * (1.f / HID);
    const float var = s2 * (1.f / HID) - mu * mu;
    const float rs = rsqrtf(var + 1e-5f);
    unsigned int pk[4];
#pragma unroll
    for (int jj = 0; jj < 4; ++jj) {
      h2 o;
      o.x = (_Float16)((v[2 * jj] - mu) * rs * g8[2 * jj] + be8[2 * jj]);
      o.y = (_Float16)((v[2 * jj + 1] - mu) * rs * g8[2 * jj + 1] + be8[2 * jj + 1]);
      union { h2 hh; unsigned int u; } c; c.hh = o;
      pk[jj] = c.u;
    }
    uint4 outv; outv.x = pk[0]; outv.y = pk[1]; outv.z = pk[2]; outv.w = pk[3];
    *(uint4*)(h + (size_t)(n0 + nd) * HID + sc * 8) = outv;
    __syncthreads();
  }
}

// ============ fallback (round-2 passing) kernels ============================
__global__ __launch_bounds__(256) void k_attn(
    const _Float16* __restrict__ h, const void* __restrict__ ei,
    const void* __restrict__ ea,
    const void* __restrict__ aw1, const void* __restrict__ ab1,
    const void* __restrict__ aw2, const void* __restrict__ ab2,
    float* __restrict__ scores, float* __restrict__ pmax,
    const int* __restrict__ flags, int lay) {
  const int fm = flags[0], im = flags[1];
  const int tid = threadIdx.x;
  const int w = tid >> 6, l = tid & 63;
  __shared__ __align__(16) _Float16 sV[4][2 * HID + EDGE_IN];
  __shared__ float sRed[4];
  unsigned int wr[136];
  {
    const size_t base = (size_t)lay * 64 * 136 + (size_t)l * 136;
#pragma unroll
    for (int i = 0; i < 136; ++i) wr[i] = load_pair(aw1, base + i, fm);
  }
  const float bias = load_scal(ab1, lay * 64 + l, fm);
  const float w2f = load_scal(aw2, lay * 64 + l, fm);
  const float b2f = load_scal(ab2, lay, fm);
  float wmax = -3.4e38f;
  unsigned int* sv32 = (unsigned int*)sV[w];
  const int stride = gridDim.x * 4;
  const int nIter = (N_EDGES + stride - 1) / stride;
  for (int it = 0; it < nIter; ++it) {
    const int e = blockIdx.x * 4 + w + it * stride;
    const bool act = (e < N_EDGES);
    if (act) {
      const int src = load_idx(ei, e, im);
      const int dst = load_idx(ei, N_EDGES + e, im);
      sv32[l] = ((const unsigned int*)(h + (size_t)src * HID))[l];
      sv32[64 + l] = ((const unsigned int*)(h + (size_t)dst * HID))[l];
      if (l < 8) sv32[128 + l] = load_pair(ea, (size_t)e * 8 + l, fm);
    }
    __syncthreads();
    if (act) {
      float a0 = bias, a1 = 0.f, a2 = 0.f, a3 = 0.f;
      const uint4* vq = (const uint4*)sv32;
#pragma unroll
      for (int qq = 0; qq < 34; ++qq) {
        uint4 v = vq[qq];
        a0 = dot2(u2h2(v.x), u2h2(wr[qq * 4 + 0]), a0);
        a1 = dot2(u2h2(v.y), u2h2(wr[qq * 4 + 1]), a1);
        a2 = dot2(u2h2(v.z), u2h2(wr[qq * 4 + 2]), a2);
        a3 = dot2(u2h2(v.w), u2h2(wr[qq * 4 + 3]), a3);
      }
      float a = (a0 + a1) + (a2 + a3);
      a = (a > 0.f) ? a : 0.2f * a;
      float s = wave_sum(a * w2f) + b2f;
      if (l == 0) scores[e] = s;
      wmax = fmaxf(wmax, s);
    }
    __syncthreads();
  }
  if (l == 0) sRed[w] = wmax;
  __syncthreads();
  if (tid == 0)
    pmax[blockIdx.x] = fmaxf(fmaxf(sRed[0], sRed[1]), fmaxf(sRed[2], sRed[3]));
}

__global__ __launch_bounds__(256) void k_msg(
    const _Float16* __restrict__ h, const void* __restrict__ ei,
    const void* __restrict__ ea,
    const void* __restrict__ mw1, const void* __restrict__ mb1,
    const void* __restrict__ mw2, const void* __restrict__ mb2,
    const float* __restrict__ scores, const float* __restrict__ gmaxp,
    float* __restrict__ numer, float* __restrict__ denom,
    const int* __restrict__ flags, int lay) {
  const int fm = flags[0], im = flags[1];
  const int tid = threadIdx.x;
  const int slot = tid >> 7, t = tid & 127;
  __shared__ __align__(16) _Float16 sV[2][HID + EDGE_IN];
  __shared__ __align__(16) _Float16 sM1b[2][HID];
  unsigned int w1[72], w2[64];
  {
    const size_t b1p = (size_t)lay * HID * 72 + (size_t)t * 72;
#pragma unroll
    for (int i = 0; i < 72; ++i) w1[i] = load_pair(mw1, b1p + i, fm);
    const size_t b2p = (size_t)lay * HID * 64 + (size_t)t * 64;
#pragma unroll
    for (int i = 0; i < 64; ++i) w2[i] = load_pair(mw2, b2p + i, fm);
  }
  const float b1 = load_scal(mb1, lay * HID + t, fm);
  const float b2 = load_scal(mb2, lay * HID + t, fm);
  const float gmax = gmaxp[0];
  unsigned int* sv32 = (unsigned int*)sV[slot];
  for (int base = blockIdx.x * 2; base < N_EDGES; base += gridDim.x * 2) {
    const int e = base + slot;
    const int src = load_idx(ei, e, im);
    const int dst = load_idx(ei, N_EDGES + e, im);
    if (t < 64) {
      sv32[t] = ((const unsigned int*)(h + (size_t)src * HID))[t];
    } else if (t < 72) {
      sv32[t] = load_pair(ea, (size_t)e * 8 + (t - 64), fm);
    }
    __syncthreads();
    float a0 = b1, a1 = 0.f, a2 = 0.f, a3 = 0.f;
    const uint4* vq = (const uint4*)sv32;
#pragma unroll
    for (int qq = 0; qq < 18; ++qq) {
      uint4 v = vq[qq];
      a0 = dot2(u2h2(v.x), u2h2(w1[qq * 4 + 0]), a0);
      a1 = dot2(u2h2(v.y), u2h2(w1[qq * 4 + 1]), a1);
      a2 = dot2(u2h2(v.z), u2h2(w1[qq * 4 + 2]), a2);
      a3 = dot2(u2h2(v.w), u2h2(w1[qq * 4 + 3]), a3);
    }
    sM1b[slot][t] = (_Float16)fmaxf((a0 + a1) + (a2 + a3), 0.f);
    __syncthreads();
    float c0 = b2, c1 = 0.f, c2 = 0.f, c3 = 0.f;
    const uint4* mq = (const uint4*)sM1b[slot];
#pragma unroll
    for (int qq = 0; qq < 16; ++qq) {
      uint4 v = mq[qq];
      c0 = dot2(u2h2(v.x), u2h2(w2[qq * 4 + 0]), c0);
      c1 = dot2(u2h2(v.y), u2h2(w2[qq * 4 + 1]), c1);
      c2 = dot2(u2h2(v.z), u2h2(w2[qq * 4 + 2]), c2);
      c3 = dot2(u2h2(v.w), u2h2(w2[qq * 4 + 3]), c3);
    }
    float msg = (c0 + c1) + (c2 + c3);
    float wgt = __expf(scores[e] - gmax);
    atomicAdd(&numer[(size_t)dst * HID + t], msg * wgt);
    if (t == 0) atomicAdd(&denom[dst], wgt);
    __syncthreads();
  }
}

__global__ __launch_bounds__(256) void k_upd(
    _Float16* __restrict__ h, const float* __restrict__ numer,
    const float* __restrict__ denom,
    const void* __restrict__ uw1, const void* __restrict__ ub1,
    const void* __restrict__ uw2, const void* __restrict__ ub2,
    const void* __restrict__ lng, const void* __restrict__ lnb,
    const int* __restrict__ flags, int lay) {
  const int fm = flags[0];
  const int tid = threadIdx.x;
  const int slot = tid >> 7, t = tid & 127;
  const int wv = (tid >> 6) & 1;
  __shared__ __align__(16) _Float16 sV[2][2 * HID];
  __shared__ __align__(16) _Float16 sM1b[2][HID];
  __shared__ float sRed[2][2][2];
  unsigned int w1[128], w2[64];
  {
    const size_t b1p = (size_t)lay * HID * 128 + (size_t)t * 128;
#pragma unroll
    for (int i = 0; i < 128; ++i) w1[i] = load_pair(uw1, b1p + i, fm);
    const size_t b2p = (size_t)lay * HID * 64 + (size_t)t * 64;
#pragma unroll
    for (int i = 0; i < 64; ++i) w2[i] = load_pair(uw2, b2p + i, fm);
  }
  const float b1 = load_scal(ub1, lay * HID + t, fm);
  const float b2 = load_scal(ub2, lay * HID + t, fm);
  const float gg = load_scal(lng, lay * HID + t, fm);
  const float bb = load_scal(lnb, lay * HID + t, fm);
  unsigned int* sv32 = (unsigned int*)sV[slot];
  for (int base = blockIdx.x * 2; base < N_NODES; base += gridDim.x * 2) {
    const int n = base + slot;
    const float inv = 1.f / (denom[n] + 1e-6f);
    if (t < 64) {
      sv32[t] = ((const unsigned int*)(h + (size_t)n * HID))[t];
    } else {
      const int j = (t - 64) * 2;
      h2 p; p.x = (_Float16)(numer[(size_t)n * HID + j] * inv);
      p.y = (_Float16)(numer[(size_t)n * HID + j + 1] * inv);
      union { h2 hh; unsigned int u; } c; c.hh = p;
      sv32[64 + (t - 64)] = c.u;
    }
    __syncthreads();
    float a0 = b1, a1 = 0.f, a2 = 0.f, a3 = 0.f;
    const uint4* vq = (const uint4*)sv32;
#pragma unroll
    for (int qq = 0; qq < 32; ++qq) {
      uint4 v = vq[qq];
      a0 = dot2(u2h2(v.x), u2h2(w1[qq * 4 + 0]), a0);
      a1 = dot2(u2h2(v.y), u2h2(w1[qq * 4 + 1]), a1);
      a2 = dot2(u2h2(v.z), u2h2(w1[qq * 4 + 2]), a2);
      a3 = dot2(u2h2(v.w), u2h2(w1[qq * 4 + 3]), a3);
    }
    sM1b[slot][t] = (_Float16)fmaxf((a0 + a1) + (a2 + a3), 0.f);
    __syncthreads();
    float c0 = b2, c1 = 0.f, c2 = 0.f, c3 = 0.f;
    const uint4* mq = (const uint4*)sM1b[slot];
#pragma unroll
    for (int qq = 0; qq < 16; ++qq) {
      uint4 v = mq[qq];
      c0 = dot2(u2h2(v.x), u2h2(w2[qq * 4 + 0]), c0);
      c1 = dot2(u2h2(v.y), u2h2(w2[qq * 4 + 1]), c1);
      c2 = dot2(u2h2(v.z), u2h2(w2[qq * 4 + 2]), c2);
      c3 = dot2(u2h2(v.w), u2h2(w2[qq * 4 + 3]), c3);
    }
    const float hold = (float)((const _Float16*)sV[slot])[t];
    const float r = fmaxf((c0 + c1) + (c2 + c3) + hold, 0.f);
    float s1 = wave_sum(r);
    float s2 = wave_sum(r * r);
    if ((tid & 63) == 0) { sRed[slot][wv][0] = s1; sRed[slot][wv][1] = s2; }
    __syncthreads();
    const float S1 = sRed[slot][0][0] + sRed[slot][1][0];
    const float S2 = sRed[slot][0][1] + sRed[slot][1][1];
    const float mu = S1 * (1.f / HID);
    const float var = S2 * (1.f / HID) - mu * mu;
    const float rs = rsqrtf(var + 1e-5f);
    h[(size_t)n * HID + t] = (_Float16)((r - mu) * rs * gg + bb);
    __syncthreads();
  }
}

// ---------------- readout ----------------------------------------------------
__global__ __launch_bounds__(256) void k_read(
    const _Float16* __restrict__ h, const void* __restrict__ gctx,
    const void* __restrict__ qw1, const void* __restrict__ qb1,
    const void* __restrict__ qw2, const void* __restrict__ qb2,
    void* __restrict__ out, const int* __restrict__ flags) {
  const int fm = flags[0];
  const int tid = threadIdx.x;
  const int slot = tid >> 7, t = tid & 127;
  const int wv = (tid >> 6) & 1;
  __shared__ __align__(16) _Float16 sV[2][HID];
  __shared__ __align__(16) _Float16 sCtx[GCTX];
  __shared__ float sRed[2][2];
  unsigned int w1[96];
#pragma unroll
  for (int i = 0; i < 96; ++i) w1[i] = load_pair(qw1, (size_t)t * 96 + i, fm);
  const float b1 = load_scal(qb1, t, fm);
  const float w2f = load_scal(qw2, t, fm);
  const float b2 = load_scal(qb2, 0, fm);
  if (tid < GCTX / 2)
    ((unsigned int*)sCtx)[tid] = load_pair(gctx, tid, fm);
  __syncthreads();
  unsigned int* sv32 = (unsigned int*)sV[slot];
  for (int base = blockIdx.x * 2; base < N_NODES; base += gridDim.x * 2) {
    const int n = base + slot;
    if (t < 64) sv32[t] = ((const unsigned int*)(h + (size_t)n * HID))[t];
    __syncthreads();
    float a0 = b1, a1 = 0.f, a2 = 0.f, a3 = 0.f;
    const uint4* vq = (const uint4*)sv32;
#pragma unroll
    for (int qq = 0; qq < 16; ++qq) {
      uint4 v = vq[qq];
      a0 = dot2(u2h2(v.x), u2h2(w1[qq * 4 + 0]), a0);
      a1 = dot2(u2h2(v.y), u2h2(w1[qq * 4 + 1]), a1);
      a2 = dot2(u2h2(v.z), u2h2(w1[qq * 4 + 2]), a2);
      a3 = dot2(u2h2(v.w), u2h2(w1[qq * 4 + 3]), a3);
    }
    const uint4* cq = (const uint4*)sCtx;
#pragma unroll
    for (int qq = 0; qq < 8; ++qq) {
      uint4 v = cq[qq];
      a0 = dot2(u2h2(v.x), u2h2(w1[64 + qq * 4 + 0]), a0);
      a1 = dot2(u2h2(v.y), u2h2(w1[64 + qq * 4 + 1]), a1);
      a2 = dot2(u2h2(v.z), u2h2(w1[64 + qq * 4 + 2]), a2);
      a3 = dot2(u2h2(v.w), u2h2(w1[64 + qq * 4 + 3]), a3);
    }
    float u = fmaxf((a0 + a1) + (a2 + a3), 0.f);
    float s = wave_sum(u * w2f);
    if ((tid & 63) == 0) sRed[slot][wv] = s;
    __syncthreads();
    if (t == 0) {
      const float val = sRed[slot][0] + sRed[slot][1] + b2;
      if (fm == 0) ((__hip_bfloat16*)out)[n] = __float2bfloat16(val);
      else if (fm == 2) ((_Float16*)out)[n] = (_Float16)val;
      else ((float*)out)[n] = val;
    }
    __syncthreads();
  }
}

extern "C" void kernel_launch(void* const* d_in, const int* in_sizes, int n_in,
                              void* d_out, int out_size, void* d_ws, size_t ws_size,
                              hipStream_t stream) {
  const void* x    = d_in[0];
  const void* ei   = d_in[1];
  const void* ea   = d_in[2];
  const void* gctx = d_in[3];
  const void* npw  = d_in[4];
  const void* npb  = d_in[5];
  const void* mw1  = d_in[6];
  const void* mb1  = d_in[7];
  const void* mw2  = d_in[8];
  const void* mb2  = d_in[9];
  const void* aw1  = d_in[10];
  const void* ab1  = d_in[11];
  const void* aw2  = d_in[12];
  const void* ab2  = d_in[13];
  const void* uw1  = d_in[14];
  const void* ub1  = d_in[15];
  const void* uw2  = d_in[16];
  const void* ub2  = d_in[17];
  const void* lng  = d_in[18];
  const void* lnb  = d_in[19];
  const void* qw1  = d_in[20];
  const void* qb1  = d_in[21];
  const void* qw2  = d_in[22];
  const void* qb2  = d_in[23];

  char* ws = (char*)d_ws;
  dim3 blk(256);

  size_t off = 0;
  auto alloc = [&](size_t bytes) {
    void* p = ws + off;
    off = (off + bytes + 255) & ~(size_t)255;
    return p;
  };
  int* flags       = (int*)alloc(8 * 4);
  _Float16* hbuf   = (_Float16*)alloc((size_t)N_NODES * HID * 2);
  float* scores    = (float*)alloc((size_t)N_EDGES * 4);
  float* pmax      = (float*)alloc(2048 * 4);
  float* gmax      = (float*)alloc(4);
  int* cnt         = (int*)alloc((size_t)N_NODES * 4);
  int* cur         = (int*)alloc((size_t)N_NODES * 4);
  int* row_ptr     = (int*)alloc((size_t)(N_NODES + 1) * 4);
  int2* sd2        = (int2*)alloc((size_t)N_EDGES * 8);
  _Float16* eaPerm = (_Float16*)alloc((size_t)N_EDGES * EDGE_IN * 2);
  _Float16* msgbuf = (_Float16*)alloc((size_t)N_EDGES * HID * 2);
  const size_t need_big = off;

  if (ws_size >= need_big) {
    // ======== MFMA + CSR-ordered path ========
    k_detect<<<1, blk, 0, stream>>>((const unsigned int*)x, (const unsigned int*)ei, flags);
    k_proj<<<1024, blk, 0, stream>>>(x, npw, npb, hbuf, flags);
    hipMemsetAsync(cnt, 0, (size_t)N_NODES * 4, stream);
    k_hist<<<1024, blk, 0, stream>>>(ei, cnt, flags);
    k_scan<<<1, blk, 0, stream>>>(cnt, row_ptr, cur);
    k_scatter<<<1024, blk, 0, stream>>>(ei, ea, cur, sd2, eaPerm, flags);
    for (int lay = 0; lay < NLAYER; ++lay) {
      k_edge<<<1024, blk, 0, stream>>>(hbuf, sd2, eaPerm, aw1, ab1, aw2, ab2,
                                       mw1, mb1, mw2, mb2, scores, pmax, msgbuf,
                                       flags, lay);
      k_rmax<<<1, blk, 0, stream>>>(pmax, 1024, gmax);
      k_gupd<<<1024, blk, 0, stream>>>(hbuf, msgbuf, scores, row_ptr,
                                       gmax, uw1, ub1, uw2, ub2, lng, lnb,
                                       flags, lay);
    }
    k_read<<<1024, blk, 0, stream>>>(hbuf, gctx, qw1, qb1, qw2, qb2, d_out, flags);
  } else {
    // ======== fallback: round-2 passing path ========
    size_t o2 = 0;
    int* flags2 = (int*)(ws + o2); o2 += 256;
    _Float16* hb = (_Float16*)(ws + o2); o2 += (size_t)N_NODES * HID * 2;
    o2 = (o2 + 255) & ~(size_t)255;
    float* sc = (float*)(ws + o2); o2 += (size_t)N_EDGES * 4;
    float* pm = (float*)(ws + o2); o2 += 1024 * 4;
    float* gm = (float*)(ws + o2); o2 += 256;
    float* numer = (float*)(ws + o2); o2 += (size_t)N_NODES * HID * 4;
    float* denom = (float*)(ws + o2); o2 += (size_t)N_NODES * 4;
    k_detect<<<1, blk, 0, stream>>>((const unsigned int*)x, (const unsigned int*)ei, flags2);
    k_proj<<<1024, blk, 0, stream>>>(x, npw, npb, hb, flags2);
    for (int lay = 0; lay < NLAYER; ++lay) {
      hipMemsetAsync(numer, 0, (size_t)N_NODES * HID * 4, stream);
      hipMemsetAsync(denom, 0, (size_t)N_NODES * 4, stream);
      k_attn<<<1024, blk, 0, stream>>>(hb, ei, ea, aw1, ab1, aw2, ab2, sc, pm,
                                       flags2, lay);
      k_rmax<<<1, blk, 0, stream>>>(pm, 1024, gm);
      k_msg<<<1024, blk, 0, stream>>>(hb, ei, ea, mw1, mb1, mw2, mb2, sc, gm,
                                      numer, denom, flags2, lay);
      k_upd<<<1024, blk, 0, stream>>>(hb, numer, denom, uw1, ub1, uw2, ub2, lng, lnb,
                                      flags2, lay);
    }
    k_read<<<1024, blk, 0, stream>>>(hb, gctx, qw1, qb1, qw2, qb2, d_out, flags2);
  }
}

// Round 9
// 1152.489 us; speedup vs baseline: 1.5267x; 1.5267x over previous
//
#include <hip/hip_runtime.h>
#include <hip/hip_bf16.h>

#define N_NODES 50000
#define N_EDGES 600000
#define NODE_IN 32
#define EDGE_IN 16
#define HID 128
#define NLAYER 3
#define GCTX 64

typedef _Float16 h2 __attribute__((ext_vector_type(2)));
typedef _Float16 f16x8 __attribute__((ext_vector_type(8)));
typedef float f32x4 __attribute__((ext_vector_type(4)));

__device__ __forceinline__ float bf2f(unsigned short u) {
  union { unsigned int i; float f; } c; c.i = ((unsigned int)u) << 16; return c.f;
}
__device__ __forceinline__ unsigned int bfp2hp(unsigned int b) {
  union { unsigned int i; float f; } lo, hi;
  lo.i = b << 16; hi.i = b & 0xffff0000u;
  h2 r; r.x = (_Float16)lo.f; r.y = (_Float16)hi.f;
  union { h2 h; unsigned int u; } c; c.h = r; return c.u;
}
__device__ __forceinline__ h2 u2h2(unsigned int u) {
  union { unsigned int u; h2 h; } c; c.u = u; return c.h;
}
__device__ __forceinline__ float dot2(h2 a, h2 b, float c) {
#if __has_builtin(__builtin_amdgcn_fdot2)
  return __builtin_amdgcn_fdot2(a, b, c, false);
#else
  return c + (float)a.x * (float)b.x + (float)a.y * (float)b.y;
#endif
}

// generic loaders: fm 0=bf16, 1=fp32, 2=fp16
__device__ __forceinline__ unsigned int load_pair(const void* p, size_t pairIdx, int fm) {
  if (fm == 0) return bfp2hp(((const unsigned int*)p)[pairIdx]);
  if (fm == 2) return ((const unsigned int*)p)[pairIdx];
  const float* f = (const float*)p;
  h2 r; r.x = (_Float16)f[2 * pairIdx]; r.y = (_Float16)f[2 * pairIdx + 1];
  union { h2 h; unsigned int u; } c; c.h = r; return c.u;
}
__device__ __forceinline__ float load_scal(const void* p, size_t idx, int fm) {
  if (fm == 0) return bf2f(((const unsigned short*)p)[idx]);
  if (fm == 2) return (float)((const _Float16*)p)[idx];
  return ((const float*)p)[idx];
}
__device__ __forceinline__ int load_idx(const void* p, size_t pos, int im) {
  if (im == 0) return ((const int*)p)[pos];
  return (int)((const long long*)p)[pos];
}
__device__ __forceinline__ uint4 zero4() { uint4 z; z.x = z.y = z.z = z.w = 0u; return z; }
__device__ __forceinline__ uint4 load8(const void* p, size_t eoff, int fm) {
  uint4 r;
  if (fm == 0) {
    uint4 t = *(const uint4*)((const unsigned short*)p + eoff);
    r.x = bfp2hp(t.x); r.y = bfp2hp(t.y); r.z = bfp2hp(t.z); r.w = bfp2hp(t.w);
  } else if (fm == 2) {
    r = *(const uint4*)((const unsigned short*)p + eoff);
  } else {
    const float* f = (const float*)p + eoff;
    h2 a, b, c, d;
    a.x = (_Float16)f[0]; a.y = (_Float16)f[1];
    b.x = (_Float16)f[2]; b.y = (_Float16)f[3];
    c.x = (_Float16)f[4]; c.y = (_Float16)f[5];
    d.x = (_Float16)f[6]; d.y = (_Float16)f[7];
    union { h2 h; unsigned int u; } ua, ub, uc, ud;
    ua.h = a; ub.h = b; uc.h = c; ud.h = d;
    r.x = ua.u; r.y = ub.u; r.z = uc.u; r.w = ud.u;
  }
  return r;
}
__device__ __forceinline__ f32x4 mfma16(uint4 a, uint4 b, f32x4 c) {
  union { uint4 u; f16x8 h; } A, B; A.u = a; B.u = b;
  return __builtin_amdgcn_mfma_f32_16x16x32_f16(A.h, B.h, c, 0, 0, 0);
}

__device__ __forceinline__ float wave_sum(float v) {
  for (int m = 32; m >= 1; m >>= 1) v += __shfl_xor(v, m, 64);
  return v;
}
__device__ __forceinline__ float wave_max(float v) {
  for (int m = 32; m >= 1; m >>= 1) v = fmaxf(v, __shfl_xor(v, m, 64));
  return v;
}

// ---------------- dtype detector -------------------------------------------
__global__ __launch_bounds__(256) void k_detect(const unsigned int* __restrict__ x,
                                                const unsigned int* __restrict__ ei,
                                                int* __restrict__ flags) {
  __shared__ int sIn, sOddNZ;
  const int tid = threadIdx.x;
  if (tid == 0) { sIn = 0; sOddNZ = 0; }
  __syncthreads();
  int cnt = 0;
  for (int i = tid; i < 2048; i += 256) {
    unsigned int d = x[i];
    float v0 = fabsf(bf2f((unsigned short)(d & 0xffff)));
    float v1 = fabsf(bf2f((unsigned short)(d >> 16)));
    if (v0 >= 0.1f && v0 <= 6.0f) cnt++;
    if (v1 >= 0.1f && v1 <= 6.0f) cnt++;
  }
  int nz = 0;
  for (int i = tid; i < 512; i += 256)
    if (ei[2 * i + 1] != 0) nz++;
  atomicAdd(&sIn, cnt);
  atomicAdd(&sOddNZ, nz);
  __syncthreads();
  if (tid == 0) {
    float frac = (float)sIn / 4096.f;
    flags[0] = (frac > 0.75f) ? 0 : ((frac >= 0.3f) ? 1 : 2);
    flags[1] = (sOddNZ < 4) ? 1 : 0;  // 1 => int64 edge_index
  }
}

// ---------------- node projection ------------------------------------------
__global__ __launch_bounds__(256) void k_proj(
    const void* __restrict__ x, const void* __restrict__ W,
    const void* __restrict__ b, _Float16* __restrict__ h,
    const int* __restrict__ flags) {
  const int fm = flags[0];
  const int tid = threadIdx.x;
  const int slot = tid >> 7;
  const int t = tid & 127;
  __shared__ __align__(16) _Float16 sX[2][NODE_IN];
  unsigned int w[16];
#pragma unroll
  for (int i = 0; i < 16; ++i) w[i] = load_pair(W, (size_t)t * 16 + i, fm);
  const float bias = load_scal(b, t, fm);
  unsigned int* sx32 = (unsigned int*)sX[slot];
  for (int base = blockIdx.x * 2; base < N_NODES; base += gridDim.x * 2) {
    const int n = base + slot;
    if (t < 16) sx32[t] = load_pair(x, (size_t)n * 16 + t, fm);
    __syncthreads();
    float a0 = bias, a1 = 0.f, a2 = 0.f, a3 = 0.f;
    const uint4* vq = (const uint4*)sx32;
#pragma unroll
    for (int q = 0; q < 4; ++q) {
      uint4 v = vq[q];
      a0 = dot2(u2h2(v.x), u2h2(w[q * 4 + 0]), a0);
      a1 = dot2(u2h2(v.y), u2h2(w[q * 4 + 1]), a1);
      a2 = dot2(u2h2(v.z), u2h2(w[q * 4 + 2]), a2);
      a3 = dot2(u2h2(v.w), u2h2(w[q * 4 + 3]), a3);
    }
    h[(size_t)n * HID + t] = (_Float16)fmaxf((a0 + a1) + (a2 + a3), 0.f);
    __syncthreads();
  }
}

// ---------------- CSR build --------------------------------------------------
__global__ __launch_bounds__(256) void k_hist(const void* __restrict__ ei,
                                              int* __restrict__ cnt,
                                              const int* __restrict__ flags) {
  const int im = flags[1];
  for (int e = blockIdx.x * 256 + threadIdx.x; e < N_EDGES; e += gridDim.x * 256)
    atomicAdd(&cnt[load_idx(ei, N_EDGES + e, im)], 1);
}
__global__ __launch_bounds__(256) void k_scan(const int* __restrict__ cnt,
                                              int* __restrict__ row_ptr,
                                              int* __restrict__ cur) {
  __shared__ int sPart[256];
  const int t = threadIdx.x;
  const int c0 = t * 196;
  const int c1 = (c0 + 196 < N_NODES) ? c0 + 196 : N_NODES;
  int s = 0;
  for (int i = c0; i < c1; ++i) s += cnt[i];
  sPart[t] = s;
  __syncthreads();
  if (t == 0) {
    int run = 0;
    for (int i = 0; i < 256; ++i) { int v = sPart[i]; sPart[i] = run; run += v; }
    row_ptr[N_NODES] = run;
  }
  __syncthreads();
  int off = sPart[t];
  for (int i = c0; i < c1; ++i) {
    row_ptr[i] = off; cur[i] = off; off += cnt[i];
  }
}
// scatter: pos<-edge; also pack (src,dst) and permuted fp16 edge_attr
__global__ __launch_bounds__(256) void k_scatter(const void* __restrict__ ei,
                                                 const void* __restrict__ ea,
                                                 int* __restrict__ cur,
                                                 int2* __restrict__ sd2,
                                                 _Float16* __restrict__ eaPerm,
                                                 const int* __restrict__ flags) {
  const int im = flags[1], fm = flags[0];
  for (int e = blockIdx.x * 256 + threadIdx.x; e < N_EDGES; e += gridDim.x * 256) {
    const int s = load_idx(ei, e, im);
    const int d = load_idx(ei, N_EDGES + e, im);
    const int pos = atomicAdd(&cur[d], 1);
    int2 sd; sd.x = s; sd.y = d;
    sd2[pos] = sd;
    uint4 lo = load8(ea, (size_t)e * 16, fm);
    uint4 hi = load8(ea, (size_t)e * 16 + 8, fm);
    *(uint4*)(eaPerm + (size_t)pos * 16) = lo;
    *(uint4*)(eaPerm + (size_t)pos * 16 + 8) = hi;
  }
}

// ================= MFMA fused edge kernel, CSR order, 32-edge tiles ==========
#define SAP 296
#define SM1P 136
#define NT32 (N_EDGES / 32)

__global__ __launch_bounds__(256) void k_edge(
    const _Float16* __restrict__ h, const int2* __restrict__ sd2,
    const _Float16* __restrict__ eaPerm,
    const void* __restrict__ aw1, const void* __restrict__ ab1,
    const void* __restrict__ aw2, const void* __restrict__ ab2,
    const void* __restrict__ mw1, const void* __restrict__ mb1,
    const void* __restrict__ mw2, const void* __restrict__ mb2,
    float* __restrict__ scores, float* __restrict__ pmax,
    _Float16* __restrict__ msgbuf, const int* __restrict__ flags, int lay) {
  const int fm = flags[0];
  const int tid = threadIdx.x;
  const int w = tid >> 6, l = tid & 63;
  const int m16 = l & 15, q = l >> 4;
  __shared__ __align__(16) _Float16 sA[2][32 * SAP];
  __shared__ __align__(16) _Float16 sM1[2][32 * SM1P];
  __shared__ float sS[2][4][32];

  // ---- weight fragments (resident in registers) ----
  uint4 bA[9], bM1[2][5], bM2[2][4];
  {
    const int arow = w * 16 + m16;
    const size_t awb = (size_t)lay * 64 * 272 + (size_t)arow * 272;
#pragma unroll
    for (int ks = 0; ks < 9; ++ks) {
      const int c0 = ks * 32 + q * 8;
      bA[ks] = (c0 < 272) ? load8(aw1, awb + c0, fm) : zero4();
    }
#pragma unroll
    for (int nt = 0; nt < 2; ++nt) {
      const int mrow = (2 * w + nt) * 16 + m16;
      const size_t m1b = (size_t)lay * 128 * 144 + (size_t)mrow * 144;
#pragma unroll
      for (int ks = 0; ks < 5; ++ks) {
        const int c0 = ks * 32 + q * 8;
        bM1[nt][ks] = (c0 < 144) ? load8(mw1, m1b + c0, fm) : zero4();
      }
      const size_t m2b = (size_t)lay * 128 * 128 + (size_t)mrow * 128;
#pragma unroll
      for (int ks = 0; ks < 4; ++ks)
        bM2[nt][ks] = load8(mw2, m2b + ks * 32 + q * 8, fm);
    }
  }
  const float ab1v = load_scal(ab1, lay * 64 + w * 16 + m16, fm);
  const float w2s  = load_scal(aw2, lay * 64 + w * 16 + m16, fm);
  const float b2f  = load_scal(ab2, lay, fm);
  float b1v[2], b2v[2];
#pragma unroll
  for (int nt = 0; nt < 2; ++nt) {
    b1v[nt] = load_scal(mb1, lay * 128 + (2 * w + nt) * 16 + m16, fm);
    b2v[nt] = load_scal(mb2, lay * 128 + (2 * w + nt) * 16 + m16, fm);
  }

  const int ide0 = tid >> 4, ch = tid & 15, ide1 = ide0 + 16;
  float lmax = -3.4e38f;
  uint4 rHs0, rHd0, rHs1, rHd1, rEa;
  const int G = gridDim.x;
  int t = blockIdx.x, pt = -1, buf = 0;

  // zero the ea padding [272:288) of both buffers once
  if (tid < 128) {
    const int b = tid >> 6, s = tid & 63;
    *(uint4*)(sA[b] + (s >> 1) * SAP + 272 + (s & 1) * 8) = zero4();
  }
  {  // prologue prefetch
    const int e0 = t * 32;
    const int2 s0 = sd2[e0 + ide0], s1 = sd2[e0 + ide1];
    rHs0 = *(const uint4*)(h + (size_t)s0.x * HID + ch * 8);
    rHd0 = *(const uint4*)(h + (size_t)s0.y * HID + ch * 8);
    rHs1 = *(const uint4*)(h + (size_t)s1.x * HID + ch * 8);
    rHd1 = *(const uint4*)(h + (size_t)s1.y * HID + ch * 8);
    if (tid < 64)
      rEa = *(const uint4*)(eaPerm + (size_t)(e0 + (tid >> 1)) * 16 + (tid & 1) * 8);
  }
  __syncthreads();  // pad zeros visible

  while (t < NT32) {
    _Float16* A = sA[buf];
    *(uint4*)(A + ide0 * SAP + ch * 8) = rHs0;
    *(uint4*)(A + ide0 * SAP + 128 + ch * 8) = rHd0;
    *(uint4*)(A + ide1 * SAP + ch * 8) = rHs1;
    *(uint4*)(A + ide1 * SAP + 128 + ch * 8) = rHd1;
    if (tid < 64)
      *(uint4*)(A + (tid >> 1) * SAP + 256 + (tid & 1) * 8) = rEa;
    __syncthreads();
    const int nxt = t + G;
    if (nxt < NT32) {  // prefetch next tile (overlaps MFMA below)
      const int e0 = nxt * 32;
      const int2 s0 = sd2[e0 + ide0], s1 = sd2[e0 + ide1];
      rHs0 = *(const uint4*)(h + (size_t)s0.x * HID + ch * 8);
      rHd0 = *(const uint4*)(h + (size_t)s0.y * HID + ch * 8);
      rHs1 = *(const uint4*)(h + (size_t)s1.x * HID + ch * 8);
      rHd1 = *(const uint4*)(h + (size_t)s1.y * HID + ch * 8);
      if (tid < 64)
        rEa = *(const uint4*)(eaPerm + (size_t)(e0 + (tid >> 1)) * 16 + (tid & 1) * 8);
    }
    // ---- phase 1 (tile t), two m-groups of 16 edges ----
#pragma unroll
    for (int mg = 0; mg < 2; ++mg) {
      const int arow = m16 + 16 * mg;
      uint4 aF[9];
#pragma unroll
      for (int ks = 0; ks < 9; ++ks)
        aF[ks] = *(const uint4*)(A + arow * SAP + ks * 32 + q * 8);
      {
        f32x4 aacc = {0.f, 0.f, 0.f, 0.f};
#pragma unroll
        for (int ks = 0; ks < 9; ++ks) aacc = mfma16(aF[ks], bA[ks], aacc);
        float sv[4];
#pragma unroll
        for (int r = 0; r < 4; ++r) {
          float v = aacc[r] + ab1v;
          v = (v > 0.f) ? v : 0.2f * v;  // leaky_relu(0.2)
          sv[r] = v * w2s;
        }
#pragma unroll
        for (int mk = 1; mk <= 8; mk <<= 1) {
#pragma unroll
          for (int r = 0; r < 4; ++r) sv[r] += __shfl_xor(sv[r], mk, 64);
        }
        if (m16 == 0)
          *(float4*)(&sS[buf][w][mg * 16 + q * 4]) = make_float4(sv[0], sv[1], sv[2], sv[3]);
      }
#pragma unroll
      for (int nt = 0; nt < 2; ++nt) {
        f32x4 macc = {0.f, 0.f, 0.f, 0.f};
#pragma unroll
        for (int ks = 0; ks < 4; ++ks) macc = mfma16(aF[ks], bM1[nt][ks], macc);
        macc = mfma16(aF[8], bM1[nt][4], macc);
        const int col = (2 * w + nt) * 16 + m16;
#pragma unroll
        for (int r = 0; r < 4; ++r)
          sM1[buf][(mg * 16 + q * 4 + r) * SM1P + col] = (_Float16)fmaxf(macc[r] + b1v[nt], 0.f);
      }
    }
    // ---- phase 2 (tile pt) ----
    if (pt >= 0) {
      const _Float16* M1 = sM1[buf ^ 1];
#pragma unroll
      for (int mg = 0; mg < 2; ++mg) {
        uint4 a2F[4];
#pragma unroll
        for (int ks = 0; ks < 4; ++ks)
          a2F[ks] = *(const uint4*)(M1 + (m16 + 16 * mg) * SM1P + ks * 32 + q * 8);
#pragma unroll
        for (int nt = 0; nt < 2; ++nt) {
          f32x4 oacc = {0.f, 0.f, 0.f, 0.f};
#pragma unroll
          for (int ks = 0; ks < 4; ++ks) oacc = mfma16(a2F[ks], bM2[nt][ks], oacc);
          const int col = (2 * w + nt) * 16 + m16;
#pragma unroll
          for (int r = 0; r < 4; ++r)
            msgbuf[(size_t)(pt * 32 + mg * 16 + q * 4 + r) * HID + col] =
                (_Float16)(oacc[r] + b2v[nt]);
        }
      }
      if (tid < 32) {
        const float s = sS[buf ^ 1][0][tid] + sS[buf ^ 1][1][tid] +
                        sS[buf ^ 1][2][tid] + sS[buf ^ 1][3][tid] + b2f;
        scores[pt * 32 + tid] = s;
        lmax = fmaxf(lmax, s);
      }
    }
    pt = t; t = nxt; buf ^= 1;
  }
  __syncthreads();
  if (pt >= 0) {  // epilogue phase 2
    const _Float16* M1 = sM1[buf ^ 1];
#pragma unroll
    for (int mg = 0; mg < 2; ++mg) {
      uint4 a2F[4];
#pragma unroll
      for (int ks = 0; ks < 4; ++ks)
        a2F[ks] = *(const uint4*)(M1 + (m16 + 16 * mg) * SM1P + ks * 32 + q * 8);
#pragma unroll
      for (int nt = 0; nt < 2; ++nt) {
        f32x4 oacc = {0.f, 0.f, 0.f, 0.f};
#pragma unroll
        for (int ks = 0; ks < 4; ++ks) oacc = mfma16(a2F[ks], bM2[nt][ks], oacc);
        const int col = (2 * w + nt) * 16 + m16;
#pragma unroll
        for (int r = 0; r < 4; ++r)
          msgbuf[(size_t)(pt * 32 + mg * 16 + q * 4 + r) * HID + col] =
              (_Float16)(oacc[r] + b2v[nt]);
      }
    }
    if (tid < 32) {
      const float s = sS[buf ^ 1][0][tid] + sS[buf ^ 1][1][tid] +
                      sS[buf ^ 1][2][tid] + sS[buf ^ 1][3][tid] + b2f;
      scores[pt * 32 + tid] = s;
      lmax = fmaxf(lmax, s);
    }
  }
  if (w == 0) {
    float m = wave_max((l < 32) ? lmax : -3.4e38f);
    if (tid == 0) pmax[blockIdx.x] = m;
  }
}

// ---------------- global max reduce -----------------------------------------
__global__ __launch_bounds__(256) void k_rmax(const float* __restrict__ pmax, int n,
                                              float* __restrict__ gmax) {
  float m = -3.4e38f;
  for (int i = threadIdx.x; i < n; i += 256) m = fmaxf(m, pmax[i]);
  m = wave_max(m);
  __shared__ float sm[4];
  if ((threadIdx.x & 63) == 0) sm[threadIdx.x >> 6] = m;
  __syncthreads();
  if (threadIdx.x == 0) gmax[0] = fmaxf(fmaxf(sm[0], sm[1]), fmaxf(sm[2], sm[3]));
}

// ============ fused softmax-gather + update MLP + residual + LN ==============
// gather = round-6 per-wave form, unroll-4 independent chains.
#define SUP 264
#define SOP 132
__global__ __launch_bounds__(256, 1) void k_gupd(
    _Float16* __restrict__ h, const _Float16* __restrict__ msgbuf,
    const float* __restrict__ scores, const int* __restrict__ row_ptr,
    const float* __restrict__ gmax,
    const void* __restrict__ uw1, const void* __restrict__ ub1,
    const void* __restrict__ uw2, const void* __restrict__ ub2,
    const void* __restrict__ lng, const void* __restrict__ lnb,
    const int* __restrict__ flags, int lay) {
  const int fm = flags[0];
  const int tid = threadIdx.x;
  const int w = tid >> 6, l = tid & 63;
  const int m16 = l & 15, q = l >> 4;
  __shared__ __align__(16) _Float16 sU[16 * SUP];
  __shared__ __align__(16) _Float16 sM1[16 * SM1P];
  __shared__ __align__(16) float sO[16 * SOP];

  uint4 bU1[2][8], bU2[2][4];
  float b1v[2], b2v[2];
#pragma unroll
  for (int nt = 0; nt < 2; ++nt) {
    const int row = w * 32 + nt * 16 + m16;
    const size_t b1p = (size_t)lay * 128 * 256 + (size_t)row * 256;
#pragma unroll
    for (int ks = 0; ks < 8; ++ks) bU1[nt][ks] = load8(uw1, b1p + ks * 32 + q * 8, fm);
    const size_t b2p = (size_t)lay * 128 * 128 + (size_t)row * 128;
#pragma unroll
    for (int ks = 0; ks < 4; ++ks) bU2[nt][ks] = load8(uw2, b2p + ks * 32 + q * 8, fm);
    b1v[nt] = load_scal(ub1, lay * 128 + row, fm);
    b2v[nt] = load_scal(ub2, lay * 128 + row, fm);
  }
  const int nd = tid >> 4, sc = tid & 15;
  float g8[8], be8[8];
#pragma unroll
  for (int j = 0; j < 8; ++j) {
    g8[j] = load_scal(lng, lay * 128 + sc * 8 + j, fm);
    be8[j] = load_scal(lnb, lay * 128 + sc * 8 + j, fm);
  }
  const float M = gmax[0];
  const unsigned int* mb32 = (const unsigned int*)msgbuf;

  for (int n0 = blockIdx.x * 16; n0 < N_NODES; n0 += gridDim.x * 16) {
    // ---- gather: wave w handles nodes n0+4w..n0+4w+3, 4 chains in flight ----
#pragma unroll
    for (int k = 0; k < 4; ++k) {
      const int n = n0 + 4 * w + k;
      const int rp0 = row_ptr[n], rp1 = row_ptr[n + 1];
      float ax0 = 0.f, ay0 = 0.f, d0s = 0.f;
      float ax1 = 0.f, ay1 = 0.f, d1s = 0.f;
      float ax2 = 0.f, ay2 = 0.f, d2s = 0.f;
      float ax3 = 0.f, ay3 = 0.f, d3s = 0.f;
      int i = rp0;
      for (; i + 4 <= rp1; i += 4) {
        const float s0 = scores[i], s1 = scores[i + 1];
        const float s2 = scores[i + 2], s3 = scores[i + 3];
        const unsigned int m0 = mb32[(size_t)i * 64 + l];
        const unsigned int m1 = mb32[(size_t)(i + 1) * 64 + l];
        const unsigned int m2 = mb32[(size_t)(i + 2) * 64 + l];
        const unsigned int m3 = mb32[(size_t)(i + 3) * 64 + l];
        const float w0 = __expf(s0 - M), w1 = __expf(s1 - M);
        const float w2 = __expf(s2 - M), w3 = __expf(s3 - M);
        h2 p0 = u2h2(m0), p1 = u2h2(m1), p2 = u2h2(m2), p3 = u2h2(m3);
        ax0 += w0 * (float)p0.x; ay0 += w0 * (float)p0.y; d0s += w0;
        ax1 += w1 * (float)p1.x; ay1 += w1 * (float)p1.y; d1s += w1;
        ax2 += w2 * (float)p2.x; ay2 += w2 * (float)p2.y; d2s += w2;
        ax3 += w3 * (float)p3.x; ay3 += w3 * (float)p3.y; d3s += w3;
      }
      for (; i < rp1; ++i) {
        const float w0 = __expf(scores[i] - M);
        h2 p0 = u2h2(mb32[(size_t)i * 64 + l]);
        ax0 += w0 * (float)p0.x; ay0 += w0 * (float)p0.y; d0s += w0;
      }
      const float ax = (ax0 + ax1) + (ax2 + ax3);
      const float ay = (ay0 + ay1) + (ay2 + ay3);
      const float den = (d0s + d1s) + (d2s + d3s);
      const float inv = 1.f / (den + 1e-6f);
      h2 o; o.x = (_Float16)(ax * inv); o.y = (_Float16)(ay * inv);
      union { h2 hh; unsigned int u; } c; c.hh = o;
      ((unsigned int*)sU)[(4 * w + k) * (SUP / 2) + 64 + l] = c.u;
    }
    {  // stage h rows (residual + MLP input)
      const int nn = 4 * w + (l >> 4), chk = l & 15;
      *(uint4*)(sU + nn * SUP + chk * 8) =
          *(const uint4*)(h + (size_t)(n0 + nn) * HID + chk * 8);
    }
    __syncthreads();
    // ---- phase 1: u = relu([h|agg] @ uw1^T + b1) ----
    uint4 aF[8];
#pragma unroll
    for (int ks = 0; ks < 8; ++ks)
      aF[ks] = *(const uint4*)(sU + m16 * SUP + ks * 32 + q * 8);
#pragma unroll
    for (int nt = 0; nt < 2; ++nt) {
      f32x4 acc = {0.f, 0.f, 0.f, 0.f};
#pragma unroll
      for (int ks = 0; ks < 8; ++ks) acc = mfma16(aF[ks], bU1[nt][ks], acc);
      const int colw = w * 32 + nt * 16 + m16;
#pragma unroll
      for (int r = 0; r < 4; ++r)
        sM1[(q * 4 + r) * SM1P + colw] = (_Float16)fmaxf(acc[r] + b1v[nt], 0.f);
    }
    __syncthreads();
    // ---- phase 2: out = u @ uw2^T + b2; r = relu(out + h) ----
    uint4 a2F[4];
#pragma unroll
    for (int ks = 0; ks < 4; ++ks)
      a2F[ks] = *(const uint4*)(sM1 + m16 * SM1P + ks * 32 + q * 8);
#pragma unroll
    for (int nt = 0; nt < 2; ++nt) {
      f32x4 acc = {0.f, 0.f, 0.f, 0.f};
#pragma unroll
      for (int ks = 0; ks < 4; ++ks) acc = mfma16(a2F[ks], bU2[nt][ks], acc);
      const int colw = w * 32 + nt * 16 + m16;
#pragma unroll
      for (int r = 0; r < 4; ++r) {
        const int row = q * 4 + r;
        const float hres = (float)sU[row * SUP + colw];
        sO[row * SOP + colw] = fmaxf(acc[r] + b2v[nt] + hres, 0.f);
      }
    }
    __syncthreads();
    // ---- layernorm: 16 threads per node ----
    float v[8], s1 = 0.f, s2 = 0.f;
    const float4 p0 = *(const float4*)(sO + nd * SOP + sc * 8);
    const float4 p1 = *(const float4*)(sO + nd * SOP + sc * 8 + 4);
    v[0] = p0.x; v[1] = p0.y; v[2] = p0.z; v[3] = p0.w;
    v[4] = p1.x; v[5] = p1.y; v[6] = p1.z; v[7] = p1.w;
#pragma unroll
    for (int j = 0; j < 8; ++j) { s1 += v[j]; s2 += v[j] * v[j]; }
#pragma unroll
    for (int mk = 1; mk <= 8; mk <<= 1) {
      s1 += __shfl_xor(s1, mk, 64);
      s2 += __shfl_xor(s2, mk, 64);
    }
    const float mu = s1 * (1.f / HID);
    const float var = s2 * (1.f / HID) - mu * mu;
    const float rs = rsqrtf(var + 1e-5f);
    unsigned int pk[4];
#pragma unroll
    for (int jj = 0; jj < 4; ++jj) {
      h2 o;
      o.x = (_Float16)((v[2 * jj] - mu) * rs * g8[2 * jj] + be8[2 * jj]);
      o.y = (_Float16)((v[2 * jj + 1] - mu) * rs * g8[2 * jj + 1] + be8[2 * jj + 1]);
      union { h2 hh; unsigned int u; } c; c.hh = o;
      pk[jj] = c.u;
    }
    uint4 outv; outv.x = pk[0]; outv.y = pk[1]; outv.z = pk[2]; outv.w = pk[3];
    *(uint4*)(h + (size_t)(n0 + nd) * HID + sc * 8) = outv;
    __syncthreads();
  }
}

// ============ fallback (round-2 passing) kernels ============================
__global__ __launch_bounds__(256) void k_attn(
    const _Float16* __restrict__ h, const void* __restrict__ ei,
    const void* __restrict__ ea,
    const void* __restrict__ aw1, const void* __restrict__ ab1,
    const void* __restrict__ aw2, const void* __restrict__ ab2,
    float* __restrict__ scores, float* __restrict__ pmax,
    const int* __restrict__ flags, int lay) {
  const int fm = flags[0], im = flags[1];
  const int tid = threadIdx.x;
  const int w = tid >> 6, l = tid & 63;
  __shared__ __align__(16) _Float16 sV[4][2 * HID + EDGE_IN];
  __shared__ float sRed[4];
  unsigned int wr[136];
  {
    const size_t base = (size_t)lay * 64 * 136 + (size_t)l * 136;
#pragma unroll
    for (int i = 0; i < 136; ++i) wr[i] = load_pair(aw1, base + i, fm);
  }
  const float bias = load_scal(ab1, lay * 64 + l, fm);
  const float w2f = load_scal(aw2, lay * 64 + l, fm);
  const float b2f = load_scal(ab2, lay, fm);
  float wmax = -3.4e38f;
  unsigned int* sv32 = (unsigned int*)sV[w];
  const int stride = gridDim.x * 4;
  const int nIter = (N_EDGES + stride - 1) / stride;
  for (int it = 0; it < nIter; ++it) {
    const int e = blockIdx.x * 4 + w + it * stride;
    const bool act = (e < N_EDGES);
    if (act) {
      const int src = load_idx(ei, e, im);
      const int dst = load_idx(ei, N_EDGES + e, im);
      sv32[l] = ((const unsigned int*)(h + (size_t)src * HID))[l];
      sv32[64 + l] = ((const unsigned int*)(h + (size_t)dst * HID))[l];
      if (l < 8) sv32[128 + l] = load_pair(ea, (size_t)e * 8 + l, fm);
    }
    __syncthreads();
    if (act) {
      float a0 = bias, a1 = 0.f, a2 = 0.f, a3 = 0.f;
      const uint4* vq = (const uint4*)sv32;
#pragma unroll
      for (int qq = 0; qq < 34; ++qq) {
        uint4 v = vq[qq];
        a0 = dot2(u2h2(v.x), u2h2(wr[qq * 4 + 0]), a0);
        a1 = dot2(u2h2(v.y), u2h2(wr[qq * 4 + 1]), a1);
        a2 = dot2(u2h2(v.z), u2h2(wr[qq * 4 + 2]), a2);
        a3 = dot2(u2h2(v.w), u2h2(wr[qq * 4 + 3]), a3);
      }
      float a = (a0 + a1) + (a2 + a3);
      a = (a > 0.f) ? a : 0.2f * a;
      float s = wave_sum(a * w2f) + b2f;
      if (l == 0) scores[e] = s;
      wmax = fmaxf(wmax, s);
    }
    __syncthreads();
  }
  if (l == 0) sRed[w] = wmax;
  __syncthreads();
  if (tid == 0)
    pmax[blockIdx.x] = fmaxf(fmaxf(sRed[0], sRed[1]), fmaxf(sRed[2], sRed[3]));
}

__global__ __launch_bounds__(256) void k_msg(
    const _Float16* __restrict__ h, const void* __restrict__ ei,
    const void* __restrict__ ea,
    const void* __restrict__ mw1, const void* __restrict__ mb1,
    const void* __restrict__ mw2, const void* __restrict__ mb2,
    const float* __restrict__ scores, const float* __restrict__ gmaxp,
    float* __restrict__ numer, float* __restrict__ denom,
    const int* __restrict__ flags, int lay) {
  const int fm = flags[0], im = flags[1];
  const int tid = threadIdx.x;
  const int slot = tid >> 7, t = tid & 127;
  __shared__ __align__(16) _Float16 sV[2][HID + EDGE_IN];
  __shared__ __align__(16) _Float16 sM1b[2][HID];
  unsigned int w1[72], w2[64];
  {
    const size_t b1p = (size_t)lay * HID * 72 + (size_t)t * 72;
#pragma unroll
    for (int i = 0; i < 72; ++i) w1[i] = load_pair(mw1, b1p + i, fm);
    const size_t b2p = (size_t)lay * HID * 64 + (size_t)t * 64;
#pragma unroll
    for (int i = 0; i < 64; ++i) w2[i] = load_pair(mw2, b2p + i, fm);
  }
  const float b1 = load_scal(mb1, lay * HID + t, fm);
  const float b2 = load_scal(mb2, lay * HID + t, fm);
  const float gmax = gmaxp[0];
  unsigned int* sv32 = (unsigned int*)sV[slot];
  for (int base = blockIdx.x * 2; base < N_EDGES; base += gridDim.x * 2) {
    const int e = base + slot;
    const int src = load_idx(ei, e, im);
    const int dst = load_idx(ei, N_EDGES + e, im);
    if (t < 64) {
      sv32[t] = ((const unsigned int*)(h + (size_t)src * HID))[t];
    } else if (t < 72) {
      sv32[t] = load_pair(ea, (size_t)e * 8 + (t - 64), fm);
    }
    __syncthreads();
    float a0 = b1, a1 = 0.f, a2 = 0.f, a3 = 0.f;
    const uint4* vq = (const uint4*)sv32;
#pragma unroll
    for (int qq = 0; qq < 18; ++qq) {
      uint4 v = vq[qq];
      a0 = dot2(u2h2(v.x), u2h2(w1[qq * 4 + 0]), a0);
      a1 = dot2(u2h2(v.y), u2h2(w1[qq * 4 + 1]), a1);
      a2 = dot2(u2h2(v.z), u2h2(w1[qq * 4 + 2]), a2);
      a3 = dot2(u2h2(v.w), u2h2(w1[qq * 4 + 3]), a3);
    }
    sM1b[slot][t] = (_Float16)fmaxf((a0 + a1) + (a2 + a3), 0.f);
    __syncthreads();
    float c0 = b2, c1 = 0.f, c2 = 0.f, c3 = 0.f;
    const uint4* mq = (const uint4*)sM1b[slot];
#pragma unroll
    for (int qq = 0; qq < 16; ++qq) {
      uint4 v = mq[qq];
      c0 = dot2(u2h2(v.x), u2h2(w2[qq * 4 + 0]), c0);
      c1 = dot2(u2h2(v.y), u2h2(w2[qq * 4 + 1]), c1);
      c2 = dot2(u2h2(v.z), u2h2(w2[qq * 4 + 2]), c2);
      c3 = dot2(u2h2(v.w), u2h2(w2[qq * 4 + 3]), c3);
    }
    float msg = (c0 + c1) + (c2 + c3);
    float wgt = __expf(scores[e] - gmax);
    atomicAdd(&numer[(size_t)dst * HID + t], msg * wgt);
    if (t == 0) atomicAdd(&denom[dst], wgt);
    __syncthreads();
  }
}

__global__ __launch_bounds__(256) void k_upd(
    _Float16* __restrict__ h, const float* __restrict__ numer,
    const float* __restrict__ denom,
    const void* __restrict__ uw1, const void* __restrict__ ub1,
    const void* __restrict__ uw2, const void* __restrict__ ub2,
    const void* __restrict__ lng, const void* __restrict__ lnb,
    const int* __restrict__ flags, int lay) {
  const int fm = flags[0];
  const int tid = threadIdx.x;
  const int slot = tid >> 7, t = tid & 127;
  const int wv = (tid >> 6) & 1;
  __shared__ __align__(16) _Float16 sV[2][2 * HID];
  __shared__ __align__(16) _Float16 sM1b[2][HID];
  __shared__ float sRed[2][2][2];
  unsigned int w1[128], w2[64];
  {
    const size_t b1p = (size_t)lay * HID * 128 + (size_t)t * 128;
#pragma unroll
    for (int i = 0; i < 128; ++i) w1[i] = load_pair(uw1, b1p + i, fm);
    const size_t b2p = (size_t)lay * HID * 64 + (size_t)t * 64;
#pragma unroll
    for (int i = 0; i < 64; ++i) w2[i] = load_pair(uw2, b2p + i, fm);
  }
  const float b1 = load_scal(ub1, lay * HID + t, fm);
  const float b2 = load_scal(ub2, lay * HID + t, fm);
  const float gg = load_scal(lng, lay * HID + t, fm);
  const float bb = load_scal(lnb, lay * HID + t, fm);
  unsigned int* sv32 = (unsigned int*)sV[slot];
  for (int base = blockIdx.x * 2; base < N_NODES; base += gridDim.x * 2) {
    const int n = base + slot;
    const float inv = 1.f / (denom[n] + 1e-6f);
    if (t < 64) {
      sv32[t] = ((const unsigned int*)(h + (size_t)n * HID))[t];
    } else {
      const int j = (t - 64) * 2;
      h2 p; p.x = (_Float16)(numer[(size_t)n * HID + j] * inv);
      p.y = (_Float16)(numer[(size_t)n * HID + j + 1] * inv);
      union { h2 hh; unsigned int u; } c; c.hh = p;
      sv32[64 + (t - 64)] = c.u;
    }
    __syncthreads();
    float a0 = b1, a1 = 0.f, a2 = 0.f, a3 = 0.f;
    const uint4* vq = (const uint4*)sv32;
#pragma unroll
    for (int qq = 0; qq < 32; ++qq) {
      uint4 v = vq[qq];
      a0 = dot2(u2h2(v.x), u2h2(w1[qq * 4 + 0]), a0);
      a1 = dot2(u2h2(v.y), u2h2(w1[qq * 4 + 1]), a1);
      a2 = dot2(u2h2(v.z), u2h2(w1[qq * 4 + 2]), a2);
      a3 = dot2(u2h2(v.w), u2h2(w1[qq * 4 + 3]), a3);
    }
    sM1b[slot][t] = (_Float16)fmaxf((a0 + a1) + (a2 + a3), 0.f);
    __syncthreads();
    float c0 = b2, c1 = 0.f, c2 = 0.f, c3 = 0.f;
    const uint4* mq = (const uint4*)sM1b[slot];
#pragma unroll
    for (int qq = 0; qq < 16; ++qq) {
      uint4 v = mq[qq];
      c0 = dot2(u2h2(v.x), u2h2(w2[qq * 4 + 0]), c0);
      c1 = dot2(u2h2(v.y), u2h2(w2[qq * 4 + 1]), c1);
      c2 = dot2(u2h2(v.z), u2h2(w2[qq * 4 + 2]), c2);
      c3 = dot2(u2h2(v.w), u2h2(w2[qq * 4 + 3]), c3);
    }
    const float hold = (float)((const _Float16*)sV[slot])[t];
    const float r = fmaxf((c0 + c1) + (c2 + c3) + hold, 0.f);
    float s1 = wave_sum(r);
    float s2 = wave_sum(r * r);
    if ((tid & 63) == 0) { sRed[slot][wv][0] = s1; sRed[slot][wv][1] = s2; }
    __syncthreads();
    const float S1 = sRed[slot][0][0] + sRed[slot][1][0];
    const float S2 = sRed[slot][0][1] + sRed[slot][1][1];
    const float mu = S1 * (1.f / HID);
    const float var = S2 * (1.f / HID) - mu * mu;
    const float rs = rsqrtf(var + 1e-5f);
    h[(size_t)n * HID + t] = (_Float16)((r - mu) * rs * gg + bb);
    __syncthreads();
  }
}

// ---------------- readout ----------------------------------------------------
__global__ __launch_bounds__(256) void k_read(
    const _Float16* __restrict__ h, const void* __restrict__ gctx,
    const void* __restrict__ qw1, const void* __restrict__ qb1,
    const void* __restrict__ qw2, const void* __restrict__ qb2,
    void* __restrict__ out, const int* __restrict__ flags) {
  const int fm = flags[0];
  const int tid = threadIdx.x;
  const int slot = tid >> 7, t = tid & 127;
  const int wv = (tid >> 6) & 1;
  __shared__ __align__(16) _Float16 sV[2][HID];
  __shared__ __align__(16) _Float16 sCtx[GCTX];
  __shared__ float sRed[2][2];
  unsigned int w1[96];
#pragma unroll
  for (int i = 0; i < 96; ++i) w1[i] = load_pair(qw1, (size_t)t * 96 + i, fm);
  const float b1 = load_scal(qb1, t, fm);
  const float w2f = load_scal(qw2, t, fm);
  const float b2 = load_scal(qb2, 0, fm);
  if (tid < GCTX / 2)
    ((unsigned int*)sCtx)[tid] = load_pair(gctx, tid, fm);
  __syncthreads();
  unsigned int* sv32 = (unsigned int*)sV[slot];
  for (int base = blockIdx.x * 2; base < N_NODES; base += gridDim.x * 2) {
    const int n = base + slot;
    if (t < 64) sv32[t] = ((const unsigned int*)(h + (size_t)n * HID))[t];
    __syncthreads();
    float a0 = b1, a1 = 0.f, a2 = 0.f, a3 = 0.f;
    const uint4* vq = (const uint4*)sv32;
#pragma unroll
    for (int qq = 0; qq < 16; ++qq) {
      uint4 v = vq[qq];
      a0 = dot2(u2h2(v.x), u2h2(w1[qq * 4 + 0]), a0);
      a1 = dot2(u2h2(v.y), u2h2(w1[qq * 4 + 1]), a1);
      a2 = dot2(u2h2(v.z), u2h2(w1[qq * 4 + 2]), a2);
      a3 = dot2(u2h2(v.w), u2h2(w1[qq * 4 + 3]), a3);
    }
    const uint4* cq = (const uint4*)sCtx;
#pragma unroll
    for (int qq = 0; qq < 8; ++qq) {
      uint4 v = cq[qq];
      a0 = dot2(u2h2(v.x), u2h2(w1[64 + qq * 4 + 0]), a0);
      a1 = dot2(u2h2(v.y), u2h2(w1[64 + qq * 4 + 1]), a1);
      a2 = dot2(u2h2(v.z), u2h2(w1[64 + qq * 4 + 2]), a2);
      a3 = dot2(u2h2(v.w), u2h2(w1[64 + qq * 4 + 3]), a3);
    }
    float u = fmaxf((a0 + a1) + (a2 + a3), 0.f);
    float s = wave_sum(u * w2f);
    if ((tid & 63) == 0) sRed[slot][wv] = s;
    __syncthreads();
    if (t == 0) {
      const float val = sRed[slot][0] + sRed[slot][1] + b2;
      if (fm == 0) ((__hip_bfloat16*)out)[n] = __float2bfloat16(val);
      else if (fm == 2) ((_Float16*)out)[n] = (_Float16)val;
      else ((float*)out)[n] = val;
    }
    __syncthreads();
  }
}

extern "C" void kernel_launch(void* const* d_in, const int* in_sizes, int n_in,
                              void* d_out, int out_size, void* d_ws, size_t ws_size,
                              hipStream_t stream) {
  const void* x    = d_in[0];
  const void* ei   = d_in[1];
  const void* ea   = d_in[2];
  const void* gctx = d_in[3];
  const void* npw  = d_in[4];
  const void* npb  = d_in[5];
  const void* mw1  = d_in[6];
  const void* mb1  = d_in[7];
  const void* mw2  = d_in[8];
  const void* mb2  = d_in[9];
  const void* aw1  = d_in[10];
  const void* ab1  = d_in[11];
  const void* aw2  = d_in[12];
  const void* ab2  = d_in[13];
  const void* uw1  = d_in[14];
  const void* ub1  = d_in[15];
  const void* uw2  = d_in[16];
  const void* ub2  = d_in[17];
  const void* lng  = d_in[18];
  const void* lnb  = d_in[19];
  const void* qw1  = d_in[20];
  const void* qb1  = d_in[21];
  const void* qw2  = d_in[22];
  const void* qb2  = d_in[23];

  char* ws = (char*)d_ws;
  dim3 blk(256);

  size_t off = 0;
  auto alloc = [&](size_t bytes) {
    void* p = ws + off;
    off = (off + bytes + 255) & ~(size_t)255;
    return p;
  };
  int* flags       = (int*)alloc(8 * 4);
  _Float16* hbuf   = (_Float16*)alloc((size_t)N_NODES * HID * 2);
  float* scores    = (float*)alloc((size_t)N_EDGES * 4);
  float* pmax      = (float*)alloc(2048 * 4);
  float* gmax      = (float*)alloc(4);
  int* cnt         = (int*)alloc((size_t)N_NODES * 4);
  int* cur         = (int*)alloc((size_t)N_NODES * 4);
  int* row_ptr     = (int*)alloc((size_t)(N_NODES + 1) * 4);
  int2* sd2        = (int2*)alloc((size_t)N_EDGES * 8);
  _Float16* eaPerm = (_Float16*)alloc((size_t)N_EDGES * EDGE_IN * 2);
  _Float16* msgbuf = (_Float16*)alloc((size_t)N_EDGES * HID * 2);
  const size_t need_big = off;

  if (ws_size >= need_big) {
    // ======== MFMA + CSR-ordered path ========
    k_detect<<<1, blk, 0, stream>>>((const unsigned int*)x, (const unsigned int*)ei, flags);
    k_proj<<<1024, blk, 0, stream>>>(x, npw, npb, hbuf, flags);
    hipMemsetAsync(cnt, 0, (size_t)N_NODES * 4, stream);
    k_hist<<<1024, blk, 0, stream>>>(ei, cnt, flags);
    k_scan<<<1, blk, 0, stream>>>(cnt, row_ptr, cur);
    k_scatter<<<1024, blk, 0, stream>>>(ei, ea, cur, sd2, eaPerm, flags);
    for (int lay = 0; lay < NLAYER; ++lay) {
      k_edge<<<1024, blk, 0, stream>>>(hbuf, sd2, eaPerm, aw1, ab1, aw2, ab2,
                                       mw1, mb1, mw2, mb2, scores, pmax, msgbuf,
                                       flags, lay);
      k_rmax<<<1, blk, 0, stream>>>(pmax, 1024, gmax);
      k_gupd<<<1024, blk, 0, stream>>>(hbuf, msgbuf, scores, row_ptr,
                                       gmax, uw1, ub1, uw2, ub2, lng, lnb,
                                       flags, lay);
    }
    k_read<<<1024, blk, 0, stream>>>(hbuf, gctx, qw1, qb1, qw2, qb2, d_out, flags);
  } else {
    // ======== fallback: round-2 passing path ========
    size_t o2 = 0;
    int* flags2 = (int*)(ws + o2); o2 += 256;
    _Float16* hb = (_Float16*)(ws + o2); o2 += (size_t)N_NODES * HID * 2;
    o2 = (o2 + 255) & ~(size_t)255;
    float* sc = (float*)(ws + o2); o2 += (size_t)N_EDGES * 4;
    float* pm = (float*)(ws + o2); o2 += 1024 * 4;
    float* gm = (float*)(ws + o2); o2 += 256;
    float* numer = (float*)(ws + o2); o2 += (size_t)N_NODES * HID * 4;
    float* denom = (float*)(ws + o2); o2 += (size_t)N_NODES * 4;
    k_detect<<<1, blk, 0, stream>>>((const unsigned int*)x, (const unsigned int*)ei, flags2);
    k_proj<<<1024, blk, 0, stream>>>(x, npw, npb, hb, flags2);
    for (int lay = 0; lay < NLAYER; ++lay) {
      hipMemsetAsync(numer, 0, (size_t)N_NODES * HID * 4, stream);
      hipMemsetAsync(denom, 0, (size_t)N_NODES * 4, stream);
      k_attn<<<1024, blk, 0, stream>>>(hb, ei, ea, aw1, ab1, aw2, ab2, sc, pm,
                                       flags2, lay);
      k_rmax<<<1, blk, 0, stream>>>(pm, 1024, gm);
      k_msg<<<1024, blk, 0, stream>>>(hb, ei, ea, mw1, mb1, mw2, mb2, sc, gm,
                                      numer, denom, flags2, lay);
      k_upd<<<1024, blk, 0, stream>>>(hb, numer, denom, uw1, ub1, uw2, ub2, lng, lnb,
                                      flags2, lay);
    }
    k_read<<<1024, blk, 0, stream>>>(hb, gctx, qw1, qb1, qw2, qb2, d_out, flags2);
  }
}

// Round 10
// 1029.669 us; speedup vs baseline: 1.7089x; 1.1193x over previous
//
#include <hip/hip_runtime.h>
#include <hip/hip_bf16.h>

#define N_NODES 50000
#define N_EDGES 600000
#define NODE_IN 32
#define EDGE_IN 16
#define HID 128
#define NLAYER 3
#define GCTX 64

typedef _Float16 h2 __attribute__((ext_vector_type(2)));
typedef _Float16 f16x8 __attribute__((ext_vector_type(8)));
typedef float f32x4 __attribute__((ext_vector_type(4)));

__device__ __forceinline__ float bf2f(unsigned short u) {
  union { unsigned int i; float f; } c; c.i = ((unsigned int)u) << 16; return c.f;
}
__device__ __forceinline__ unsigned int bfp2hp(unsigned int b) {
  union { unsigned int i; float f; } lo, hi;
  lo.i = b << 16; hi.i = b & 0xffff0000u;
  h2 r; r.x = (_Float16)lo.f; r.y = (_Float16)hi.f;
  union { h2 h; unsigned int u; } c; c.h = r; return c.u;
}
__device__ __forceinline__ h2 u2h2(unsigned int u) {
  union { unsigned int u; h2 h; } c; c.u = u; return c.h;
}
__device__ __forceinline__ float dot2(h2 a, h2 b, float c) {
#if __has_builtin(__builtin_amdgcn_fdot2)
  return __builtin_amdgcn_fdot2(a, b, c, false);
#else
  return c + (float)a.x * (float)b.x + (float)a.y * (float)b.y;
#endif
}

// generic loaders: fm 0=bf16, 1=fp32, 2=fp16
__device__ __forceinline__ unsigned int load_pair(const void* p, size_t pairIdx, int fm) {
  if (fm == 0) return bfp2hp(((const unsigned int*)p)[pairIdx]);
  if (fm == 2) return ((const unsigned int*)p)[pairIdx];
  const float* f = (const float*)p;
  h2 r; r.x = (_Float16)f[2 * pairIdx]; r.y = (_Float16)f[2 * pairIdx + 1];
  union { h2 h; unsigned int u; } c; c.h = r; return c.u;
}
__device__ __forceinline__ float load_scal(const void* p, size_t idx, int fm) {
  if (fm == 0) return bf2f(((const unsigned short*)p)[idx]);
  if (fm == 2) return (float)((const _Float16*)p)[idx];
  return ((const float*)p)[idx];
}
__device__ __forceinline__ int load_idx(const void* p, size_t pos, int im) {
  if (im == 0) return ((const int*)p)[pos];
  return (int)((const long long*)p)[pos];
}
__device__ __forceinline__ uint4 zero4() { uint4 z; z.x = z.y = z.z = z.w = 0u; return z; }
__device__ __forceinline__ uint4 load8(const void* p, size_t eoff, int fm) {
  uint4 r;
  if (fm == 0) {
    uint4 t = *(const uint4*)((const unsigned short*)p + eoff);
    r.x = bfp2hp(t.x); r.y = bfp2hp(t.y); r.z = bfp2hp(t.z); r.w = bfp2hp(t.w);
  } else if (fm == 2) {
    r = *(const uint4*)((const unsigned short*)p + eoff);
  } else {
    const float* f = (const float*)p + eoff;
    h2 a, b, c, d;
    a.x = (_Float16)f[0]; a.y = (_Float16)f[1];
    b.x = (_Float16)f[2]; b.y = (_Float16)f[3];
    c.x = (_Float16)f[4]; c.y = (_Float16)f[5];
    d.x = (_Float16)f[6]; d.y = (_Float16)f[7];
    union { h2 h; unsigned int u; } ua, ub, uc, ud;
    ua.h = a; ub.h = b; uc.h = c; ud.h = d;
    r.x = ua.u; r.y = ub.u; r.z = uc.u; r.w = ud.u;
  }
  return r;
}
__device__ __forceinline__ f32x4 mfma16(uint4 a, uint4 b, f32x4 c) {
  union { uint4 u; f16x8 h; } A, B; A.u = a; B.u = b;
  return __builtin_amdgcn_mfma_f32_16x16x32_f16(A.h, B.h, c, 0, 0, 0);
}

__device__ __forceinline__ float wave_sum(float v) {
  for (int m = 32; m >= 1; m >>= 1) v += __shfl_xor(v, m, 64);
  return v;
}
__device__ __forceinline__ float wave_max(float v) {
  for (int m = 32; m >= 1; m >>= 1) v = fmaxf(v, __shfl_xor(v, m, 64));
  return v;
}

// ---------------- dtype detector -------------------------------------------
__global__ __launch_bounds__(256) void k_detect(const unsigned int* __restrict__ x,
                                                const unsigned int* __restrict__ ei,
                                                int* __restrict__ flags) {
  __shared__ int sIn, sOddNZ;
  const int tid = threadIdx.x;
  if (tid == 0) { sIn = 0; sOddNZ = 0; }
  __syncthreads();
  int cnt = 0;
  for (int i = tid; i < 2048; i += 256) {
    unsigned int d = x[i];
    float v0 = fabsf(bf2f((unsigned short)(d & 0xffff)));
    float v1 = fabsf(bf2f((unsigned short)(d >> 16)));
    if (v0 >= 0.1f && v0 <= 6.0f) cnt++;
    if (v1 >= 0.1f && v1 <= 6.0f) cnt++;
  }
  int nz = 0;
  for (int i = tid; i < 512; i += 256)
    if (ei[2 * i + 1] != 0) nz++;
  atomicAdd(&sIn, cnt);
  atomicAdd(&sOddNZ, nz);
  __syncthreads();
  if (tid == 0) {
    float frac = (float)sIn / 4096.f;
    flags[0] = (frac > 0.75f) ? 0 : ((frac >= 0.3f) ? 1 : 2);
    flags[1] = (sOddNZ < 4) ? 1 : 0;  // 1 => int64 edge_index
  }
}

// ---------------- node projection ------------------------------------------
__global__ __launch_bounds__(256) void k_proj(
    const void* __restrict__ x, const void* __restrict__ W,
    const void* __restrict__ b, _Float16* __restrict__ h,
    const int* __restrict__ flags) {
  const int fm = flags[0];
  const int tid = threadIdx.x;
  const int slot = tid >> 7;
  const int t = tid & 127;
  __shared__ __align__(16) _Float16 sX[2][NODE_IN];
  unsigned int w[16];
#pragma unroll
  for (int i = 0; i < 16; ++i) w[i] = load_pair(W, (size_t)t * 16 + i, fm);
  const float bias = load_scal(b, t, fm);
  unsigned int* sx32 = (unsigned int*)sX[slot];
  for (int base = blockIdx.x * 2; base < N_NODES; base += gridDim.x * 2) {
    const int n = base + slot;
    if (t < 16) sx32[t] = load_pair(x, (size_t)n * 16 + t, fm);
    __syncthreads();
    float a0 = bias, a1 = 0.f, a2 = 0.f, a3 = 0.f;
    const uint4* vq = (const uint4*)sx32;
#pragma unroll
    for (int q = 0; q < 4; ++q) {
      uint4 v = vq[q];
      a0 = dot2(u2h2(v.x), u2h2(w[q * 4 + 0]), a0);
      a1 = dot2(u2h2(v.y), u2h2(w[q * 4 + 1]), a1);
      a2 = dot2(u2h2(v.z), u2h2(w[q * 4 + 2]), a2);
      a3 = dot2(u2h2(v.w), u2h2(w[q * 4 + 3]), a3);
    }
    h[(size_t)n * HID + t] = (_Float16)fmaxf((a0 + a1) + (a2 + a3), 0.f);
    __syncthreads();
  }
}

// ---------------- CSR build --------------------------------------------------
__global__ __launch_bounds__(256) void k_hist(const void* __restrict__ ei,
                                              int* __restrict__ cnt,
                                              const int* __restrict__ flags) {
  const int im = flags[1];
  for (int e = blockIdx.x * 256 + threadIdx.x; e < N_EDGES; e += gridDim.x * 256)
    atomicAdd(&cnt[load_idx(ei, N_EDGES + e, im)], 1);
}
__global__ __launch_bounds__(256) void k_scan(const int* __restrict__ cnt,
                                              int* __restrict__ row_ptr,
                                              int* __restrict__ cur) {
  __shared__ int sPart[256];
  const int t = threadIdx.x;
  const int c0 = t * 196;
  const int c1 = (c0 + 196 < N_NODES) ? c0 + 196 : N_NODES;
  int s = 0;
  for (int i = c0; i < c1; ++i) s += cnt[i];
  sPart[t] = s;
  __syncthreads();
  if (t == 0) {
    int run = 0;
    for (int i = 0; i < 256; ++i) { int v = sPart[i]; sPart[i] = run; run += v; }
    row_ptr[N_NODES] = run;
  }
  __syncthreads();
  int off = sPart[t];
  for (int i = c0; i < c1; ++i) {
    row_ptr[i] = off; cur[i] = off; off += cnt[i];
  }
}
__global__ __launch_bounds__(256) void k_scatter(const void* __restrict__ ei,
                                                 const void* __restrict__ ea,
                                                 int* __restrict__ cur,
                                                 int2* __restrict__ sd2,
                                                 _Float16* __restrict__ eaPerm,
                                                 const int* __restrict__ flags) {
  const int im = flags[1], fm = flags[0];
  for (int e = blockIdx.x * 256 + threadIdx.x; e < N_EDGES; e += gridDim.x * 256) {
    const int s = load_idx(ei, e, im);
    const int d = load_idx(ei, N_EDGES + e, im);
    const int pos = atomicAdd(&cur[d], 1);
    int2 sd; sd.x = s; sd.y = d;
    sd2[pos] = sd;
    uint4 lo = load8(ea, (size_t)e * 16, fm);
    uint4 hi = load8(ea, (size_t)e * 16 + 8, fm);
    *(uint4*)(eaPerm + (size_t)pos * 16) = lo;
    *(uint4*)(eaPerm + (size_t)pos * 16 + 8) = hi;
  }
}

// ====== MFMA fused edge kernel, CSR order, 32-edge tiles, m1 output =========
// msgbuf stores m1 = relu(mw1@[hs|ea]+b1); mw2 is applied per-NODE in k_upd3.
#define SAP 296
#define SM1P 136
#define NT32 (N_EDGES / 32)

__global__ __launch_bounds__(256) void k_edge(
    const _Float16* __restrict__ h, const int2* __restrict__ sd2,
    const _Float16* __restrict__ eaPerm,
    const void* __restrict__ aw1, const void* __restrict__ ab1,
    const void* __restrict__ aw2, const void* __restrict__ ab2,
    const void* __restrict__ mw1, const void* __restrict__ mb1,
    float* __restrict__ scores, float* __restrict__ pmax,
    _Float16* __restrict__ msgbuf, const int* __restrict__ flags, int lay) {
  const int fm = flags[0];
  const int tid = threadIdx.x;
  const int w = tid >> 6, l = tid & 63;
  const int m16 = l & 15, q = l >> 4;
  __shared__ __align__(16) _Float16 sA[2][32 * SAP];
  __shared__ float sS[2][4][32];

  // ---- weight fragments (resident in registers) ----
  uint4 bA[9], bM1[2][5];
  {
    const int arow = w * 16 + m16;
    const size_t awb = (size_t)lay * 64 * 272 + (size_t)arow * 272;
#pragma unroll
    for (int ks = 0; ks < 9; ++ks) {
      const int c0 = ks * 32 + q * 8;
      bA[ks] = (c0 < 272) ? load8(aw1, awb + c0, fm) : zero4();
    }
#pragma unroll
    for (int nt = 0; nt < 2; ++nt) {
      const int mrow = (2 * w + nt) * 16 + m16;
      const size_t m1b = (size_t)lay * 128 * 144 + (size_t)mrow * 144;
#pragma unroll
      for (int ks = 0; ks < 5; ++ks) {
        const int c0 = ks * 32 + q * 8;
        bM1[nt][ks] = (c0 < 144) ? load8(mw1, m1b + c0, fm) : zero4();
      }
    }
  }
  const float ab1v = load_scal(ab1, lay * 64 + w * 16 + m16, fm);
  const float w2s  = load_scal(aw2, lay * 64 + w * 16 + m16, fm);
  const float b2f  = load_scal(ab2, lay, fm);
  float b1v[2];
#pragma unroll
  for (int nt = 0; nt < 2; ++nt)
    b1v[nt] = load_scal(mb1, lay * 128 + (2 * w + nt) * 16 + m16, fm);

  const int ide0 = tid >> 4, ch = tid & 15, ide1 = ide0 + 16;
  float lmax = -3.4e38f;
  uint4 rHs0, rHd0, rHs1, rHd1, rEa;
  const int G = gridDim.x;
  int t = blockIdx.x, pt = -1, buf = 0;

  // zero the ea padding [272:288) of both buffers once
  if (tid < 128) {
    const int b = tid >> 6, s = tid & 63;
    *(uint4*)(sA[b] + (s >> 1) * SAP + 272 + (s & 1) * 8) = zero4();
  }
  {  // prologue prefetch
    const int e0 = t * 32;
    const int2 s0 = sd2[e0 + ide0], s1 = sd2[e0 + ide1];
    rHs0 = *(const uint4*)(h + (size_t)s0.x * HID + ch * 8);
    rHd0 = *(const uint4*)(h + (size_t)s0.y * HID + ch * 8);
    rHs1 = *(const uint4*)(h + (size_t)s1.x * HID + ch * 8);
    rHd1 = *(const uint4*)(h + (size_t)s1.y * HID + ch * 8);
    if (tid < 64)
      rEa = *(const uint4*)(eaPerm + (size_t)(e0 + (tid >> 1)) * 16 + (tid & 1) * 8);
  }
  __syncthreads();  // pad zeros visible

  while (t < NT32) {
    _Float16* A = sA[buf];
    *(uint4*)(A + ide0 * SAP + ch * 8) = rHs0;
    *(uint4*)(A + ide0 * SAP + 128 + ch * 8) = rHd0;
    *(uint4*)(A + ide1 * SAP + ch * 8) = rHs1;
    *(uint4*)(A + ide1 * SAP + 128 + ch * 8) = rHd1;
    if (tid < 64)
      *(uint4*)(A + (tid >> 1) * SAP + 256 + (tid & 1) * 8) = rEa;
    __syncthreads();
    const int nxt = t + G;
    if (nxt < NT32) {  // prefetch next tile (overlaps MFMA below)
      const int e0 = nxt * 32;
      const int2 s0 = sd2[e0 + ide0], s1 = sd2[e0 + ide1];
      rHs0 = *(const uint4*)(h + (size_t)s0.x * HID + ch * 8);
      rHd0 = *(const uint4*)(h + (size_t)s0.y * HID + ch * 8);
      rHs1 = *(const uint4*)(h + (size_t)s1.x * HID + ch * 8);
      rHd1 = *(const uint4*)(h + (size_t)s1.y * HID + ch * 8);
      if (tid < 64)
        rEa = *(const uint4*)(eaPerm + (size_t)(e0 + (tid >> 1)) * 16 + (tid & 1) * 8);
    }
    // ---- phase 1 (tile t), two m-groups of 16 edges ----
#pragma unroll
    for (int mg = 0; mg < 2; ++mg) {
      const int arow = m16 + 16 * mg;
      uint4 aF[9];
#pragma unroll
      for (int ks = 0; ks < 9; ++ks)
        aF[ks] = *(const uint4*)(A + arow * SAP + ks * 32 + q * 8);
      {
        f32x4 aacc = {0.f, 0.f, 0.f, 0.f};
#pragma unroll
        for (int ks = 0; ks < 9; ++ks) aacc = mfma16(aF[ks], bA[ks], aacc);
        float sv[4];
#pragma unroll
        for (int r = 0; r < 4; ++r) {
          float v = aacc[r] + ab1v;
          v = (v > 0.f) ? v : 0.2f * v;  // leaky_relu(0.2)
          sv[r] = v * w2s;
        }
#pragma unroll
        for (int mk = 1; mk <= 8; mk <<= 1) {
#pragma unroll
          for (int r = 0; r < 4; ++r) sv[r] += __shfl_xor(sv[r], mk, 64);
        }
        if (m16 == 0)
          *(float4*)(&sS[buf][w][mg * 16 + q * 4]) = make_float4(sv[0], sv[1], sv[2], sv[3]);
      }
#pragma unroll
      for (int nt = 0; nt < 2; ++nt) {
        f32x4 macc = {0.f, 0.f, 0.f, 0.f};
#pragma unroll
        for (int ks = 0; ks < 4; ++ks) macc = mfma16(aF[ks], bM1[nt][ks], macc);
        macc = mfma16(aF[8], bM1[nt][4], macc);
        const int col = (2 * w + nt) * 16 + m16;
#pragma unroll
        for (int r = 0; r < 4; ++r)
          msgbuf[(size_t)(t * 32 + mg * 16 + q * 4 + r) * HID + col] =
              (_Float16)fmaxf(macc[r] + b1v[nt], 0.f);
      }
    }
    // ---- deferred score finalize (tile pt, sS from previous iteration) ----
    if (pt >= 0 && tid < 32) {
      const float s = sS[buf ^ 1][0][tid] + sS[buf ^ 1][1][tid] +
                      sS[buf ^ 1][2][tid] + sS[buf ^ 1][3][tid] + b2f;
      scores[pt * 32 + tid] = s;
      lmax = fmaxf(lmax, s);
    }
    pt = t; t = nxt; buf ^= 1;
  }
  __syncthreads();
  if (pt >= 0 && tid < 32) {  // epilogue score finalize
    const float s = sS[buf ^ 1][0][tid] + sS[buf ^ 1][1][tid] +
                    sS[buf ^ 1][2][tid] + sS[buf ^ 1][3][tid] + b2f;
    scores[pt * 32 + tid] = s;
    lmax = fmaxf(lmax, s);
  }
  if (w == 0) {
    float m = wave_max((l < 32) ? lmax : -3.4e38f);
    if (tid == 0) pmax[blockIdx.x] = m;
  }
}

// ---------------- global max reduce -----------------------------------------
__global__ __launch_bounds__(256) void k_rmax(const float* __restrict__ pmax, int n,
                                              float* __restrict__ gmax) {
  float m = -3.4e38f;
  for (int i = threadIdx.x; i < n; i += 256) m = fmaxf(m, pmax[i]);
  m = wave_max(m);
  __shared__ float sm[4];
  if ((threadIdx.x & 63) == 0) sm[threadIdx.x >> 6] = m;
  __syncthreads();
  if (threadIdx.x == 0) gmax[0] = fmaxf(fmaxf(sm[0], sm[1]), fmaxf(sm[2], sm[3]));
}

// ============ weight-free streaming gather: S = Σ w·m1, D = Σ w ==============
__global__ __launch_bounds__(256) void k_gather(
    const _Float16* __restrict__ msgbuf, const float* __restrict__ scores,
    const int* __restrict__ row_ptr, const float* __restrict__ gmax,
    _Float16* __restrict__ Sbuf, float* __restrict__ Dbuf) {
  const int w = threadIdx.x >> 6, l = threadIdx.x & 63;
  const int n0 = blockIdx.x * 16;
  const float M = gmax[0];
  const unsigned int* mb32 = (const unsigned int*)msgbuf;
#pragma unroll
  for (int k = 0; k < 4; ++k) {
    const int n = n0 + 4 * w + k;
    const int rp0 = row_ptr[n], rp1 = row_ptr[n + 1];
    float ax0 = 0.f, ay0 = 0.f, d0s = 0.f;
    float ax1 = 0.f, ay1 = 0.f, d1s = 0.f;
    float ax2 = 0.f, ay2 = 0.f, d2s = 0.f;
    float ax3 = 0.f, ay3 = 0.f, d3s = 0.f;
    int i = rp0;
    for (; i + 4 <= rp1; i += 4) {
      const float s0 = scores[i], s1 = scores[i + 1];
      const float s2 = scores[i + 2], s3 = scores[i + 3];
      const unsigned int m0 = mb32[(size_t)i * 64 + l];
      const unsigned int m1 = mb32[(size_t)(i + 1) * 64 + l];
      const unsigned int m2 = mb32[(size_t)(i + 2) * 64 + l];
      const unsigned int m3 = mb32[(size_t)(i + 3) * 64 + l];
      const float w0 = __expf(s0 - M), w1 = __expf(s1 - M);
      const float w2 = __expf(s2 - M), w3 = __expf(s3 - M);
      h2 p0 = u2h2(m0), p1 = u2h2(m1), p2 = u2h2(m2), p3 = u2h2(m3);
      ax0 += w0 * (float)p0.x; ay0 += w0 * (float)p0.y; d0s += w0;
      ax1 += w1 * (float)p1.x; ay1 += w1 * (float)p1.y; d1s += w1;
      ax2 += w2 * (float)p2.x; ay2 += w2 * (float)p2.y; d2s += w2;
      ax3 += w3 * (float)p3.x; ay3 += w3 * (float)p3.y; d3s += w3;
    }
    for (; i < rp1; ++i) {
      const float w0 = __expf(scores[i] - M);
      h2 p0 = u2h2(mb32[(size_t)i * 64 + l]);
      ax0 += w0 * (float)p0.x; ay0 += w0 * (float)p0.y; d0s += w0;
    }
    const float ax = (ax0 + ax1) + (ax2 + ax3);
    const float ay = (ay0 + ay1) + (ay2 + ay3);
    const float den = (d0s + d1s) + (d2s + d3s);
    h2 o; o.x = (_Float16)ax; o.y = (_Float16)ay;
    union { h2 hh; unsigned int u; } c; c.hh = o;
    ((unsigned int*)Sbuf)[(size_t)n * 64 + l] = c.u;
    if (l == 0) Dbuf[n] = den;
  }
}

// ===== dense per-node: agg=(mw2@S+b2·D)/(D+eps) → update MLP → LN ===========
// sU row: [h 0:128 | S 128:256 | agg 256:384], stride SUP3 halves.
#define SUP3 392
#define SOP 132
__global__ __launch_bounds__(256, 1) void k_upd3(
    _Float16* __restrict__ h, const _Float16* __restrict__ Sbuf,
    const float* __restrict__ Dbuf,
    const void* __restrict__ mw2, const void* __restrict__ mb2,
    const void* __restrict__ uw1, const void* __restrict__ ub1,
    const void* __restrict__ uw2, const void* __restrict__ ub2,
    const void* __restrict__ lng, const void* __restrict__ lnb,
    const int* __restrict__ flags, int lay) {
  const int fm = flags[0];
  const int tid = threadIdx.x;
  const int w = tid >> 6, l = tid & 63;
  const int m16 = l & 15, q = l >> 4;
  __shared__ __align__(16) _Float16 sU[16 * SUP3];
  __shared__ __align__(16) _Float16 sM1[16 * SM1P];
  __shared__ __align__(16) float sO[16 * SOP];
  __shared__ float sD[16];

  uint4 bU1[2][8], bU2[2][4], bM2g[2][4];
  float b1v[2], b2v[2], b2m[2];
#pragma unroll
  for (int nt = 0; nt < 2; ++nt) {
    const int row = w * 32 + nt * 16 + m16;
    const size_t b1p = (size_t)lay * 128 * 256 + (size_t)row * 256;
#pragma unroll
    for (int ks = 0; ks < 8; ++ks) bU1[nt][ks] = load8(uw1, b1p + ks * 32 + q * 8, fm);
    const size_t b2p = (size_t)lay * 128 * 128 + (size_t)row * 128;
#pragma unroll
    for (int ks = 0; ks < 4; ++ks) bU2[nt][ks] = load8(uw2, b2p + ks * 32 + q * 8, fm);
#pragma unroll
    for (int ks = 0; ks < 4; ++ks) bM2g[nt][ks] = load8(mw2, b2p + ks * 32 + q * 8, fm);
    b1v[nt] = load_scal(ub1, lay * 128 + row, fm);
    b2v[nt] = load_scal(ub2, lay * 128 + row, fm);
    b2m[nt] = load_scal(mb2, lay * 128 + row, fm);
  }
  const int nd = tid >> 4, sc = tid & 15;
  float g8[8], be8[8];
#pragma unroll
  for (int j = 0; j < 8; ++j) {
    g8[j] = load_scal(lng, lay * 128 + sc * 8 + j, fm);
    be8[j] = load_scal(lnb, lay * 128 + sc * 8 + j, fm);
  }

  for (int n0 = blockIdx.x * 16; n0 < N_NODES; n0 += gridDim.x * 16) {
    // ---- stage: h rows, S rows, D ----
    *(uint4*)(sU + nd * SUP3 + sc * 8) =
        *(const uint4*)(h + (size_t)(n0 + nd) * HID + sc * 8);
    *(uint4*)(sU + nd * SUP3 + 128 + sc * 8) =
        *(const uint4*)(Sbuf + (size_t)(n0 + nd) * HID + sc * 8);
    if (tid < 16) sD[tid] = Dbuf[n0 + tid];
    __syncthreads();
    // ---- phase 0: agg = (mw2 @ S + b2m·D) / (D + eps) ----
    {
      uint4 aS[4];
#pragma unroll
      for (int ks = 0; ks < 4; ++ks)
        aS[ks] = *(const uint4*)(sU + m16 * SUP3 + 128 + ks * 32 + q * 8);
#pragma unroll
      for (int nt = 0; nt < 2; ++nt) {
        f32x4 acc = {0.f, 0.f, 0.f, 0.f};
#pragma unroll
        for (int ks = 0; ks < 4; ++ks) acc = mfma16(aS[ks], bM2g[nt][ks], acc);
        const int colw = w * 32 + nt * 16 + m16;
#pragma unroll
        for (int r = 0; r < 4; ++r) {
          const int row = q * 4 + r;
          const float Dv = sD[row];
          const float inv = 1.f / (Dv + 1e-6f);
          sU[row * SUP3 + 256 + colw] = (_Float16)((acc[r] + b2m[nt] * Dv) * inv);
        }
      }
    }
    __syncthreads();
    // ---- phase 1: u = relu([h|agg] @ uw1^T + b1) ----
    uint4 aF[8];
#pragma unroll
    for (int ks = 0; ks < 4; ++ks)
      aF[ks] = *(const uint4*)(sU + m16 * SUP3 + ks * 32 + q * 8);
#pragma unroll
    for (int ks = 4; ks < 8; ++ks)
      aF[ks] = *(const uint4*)(sU + m16 * SUP3 + 256 + (ks - 4) * 32 + q * 8);
#pragma unroll
    for (int nt = 0; nt < 2; ++nt) {
      f32x4 acc = {0.f, 0.f, 0.f, 0.f};
#pragma unroll
      for (int ks = 0; ks < 8; ++ks) acc = mfma16(aF[ks], bU1[nt][ks], acc);
      const int colw = w * 32 + nt * 16 + m16;
#pragma unroll
      for (int r = 0; r < 4; ++r)
        sM1[(q * 4 + r) * SM1P + colw] = (_Float16)fmaxf(acc[r] + b1v[nt], 0.f);
    }
    __syncthreads();
    // ---- phase 2: out = u @ uw2^T + b2; r = relu(out + h) ----
    uint4 a2F[4];
#pragma unroll
    for (int ks = 0; ks < 4; ++ks)
      a2F[ks] = *(const uint4*)(sM1 + m16 * SM1P + ks * 32 + q * 8);
#pragma unroll
    for (int nt = 0; nt < 2; ++nt) {
      f32x4 acc = {0.f, 0.f, 0.f, 0.f};
#pragma unroll
      for (int ks = 0; ks < 4; ++ks) acc = mfma16(a2F[ks], bU2[nt][ks], acc);
      const int colw = w * 32 + nt * 16 + m16;
#pragma unroll
      for (int r = 0; r < 4; ++r) {
        const int row = q * 4 + r;
        const float hres = (float)sU[row * SUP3 + colw];
        sO[row * SOP + colw] = fmaxf(acc[r] + b2v[nt] + hres, 0.f);
      }
    }
    __syncthreads();
    // ---- layernorm: 16 threads per node ----
    float v[8], s1 = 0.f, s2 = 0.f;
    const float4 p0 = *(const float4*)(sO + nd * SOP + sc * 8);
    const float4 p1 = *(const float4*)(sO + nd * SOP + sc * 8 + 4);
    v[0] = p0.x; v[1] = p0.y; v[2] = p0.z; v[3] = p0.w;
    v[4] = p1.x; v[5] = p1.y; v[6] = p1.z; v[7] = p1.w;
#pragma unroll
    for (int j = 0; j < 8; ++j) { s1 += v[j]; s2 += v[j] * v[j]; }
#pragma unroll
    for (int mk = 1; mk <= 8; mk <<= 1) {
      s1 += __shfl_xor(s1, mk, 64);
      s2 += __shfl_xor(s2, mk, 64);
    }
    const float mu = s1 * (1.f / HID);
    const float var = s2 * (1.f / HID) - mu * mu;
    const float rs = rsqrtf(var + 1e-5f);
    unsigned int pk[4];
#pragma unroll
    for (int jj = 0; jj < 4; ++jj) {
      h2 o;
      o.x = (_Float16)((v[2 * jj] - mu) * rs * g8[2 * jj] + be8[2 * jj]);
      o.y = (_Float16)((v[2 * jj + 1] - mu) * rs * g8[2 * jj + 1] + be8[2 * jj + 1]);
      union { h2 hh; unsigned int u; } c; c.hh = o;
      pk[jj] = c.u;
    }
    uint4 outv; outv.x = pk[0]; outv.y = pk[1]; outv.z = pk[2]; outv.w = pk[3];
    *(uint4*)(h + (size_t)(n0 + nd) * HID + sc * 8) = outv;
    __syncthreads();
  }
}

// ============ fallback (round-2 passing) kernels ============================
__global__ __launch_bounds__(256) void k_attn(
    const _Float16* __restrict__ h, const void* __restrict__ ei,
    const void* __restrict__ ea,
    const void* __restrict__ aw1, const void* __restrict__ ab1,
    const void* __restrict__ aw2, const void* __restrict__ ab2,
    float* __restrict__ scores, float* __restrict__ pmax,
    const int* __restrict__ flags, int lay) {
  const int fm = flags[0], im = flags[1];
  const int tid = threadIdx.x;
  const int w = tid >> 6, l = tid & 63;
  __shared__ __align__(16) _Float16 sV[4][2 * HID + EDGE_IN];
  __shared__ float sRed[4];
  unsigned int wr[136];
  {
    const size_t base = (size_t)lay * 64 * 136 + (size_t)l * 136;
#pragma unroll
    for (int i = 0; i < 136; ++i) wr[i] = load_pair(aw1, base + i, fm);
  }
  const float bias = load_scal(ab1, lay * 64 + l, fm);
  const float w2f = load_scal(aw2, lay * 64 + l, fm);
  const float b2f = load_scal(ab2, lay, fm);
  float wmax = -3.4e38f;
  unsigned int* sv32 = (unsigned int*)sV[w];
  const int stride = gridDim.x * 4;
  const int nIter = (N_EDGES + stride - 1) / stride;
  for (int it = 0; it < nIter; ++it) {
    const int e = blockIdx.x * 4 + w + it * stride;
    const bool act = (e < N_EDGES);
    if (act) {
      const int src = load_idx(ei, e, im);
      const int dst = load_idx(ei, N_EDGES + e, im);
      sv32[l] = ((const unsigned int*)(h + (size_t)src * HID))[l];
      sv32[64 + l] = ((const unsigned int*)(h + (size_t)dst * HID))[l];
      if (l < 8) sv32[128 + l] = load_pair(ea, (size_t)e * 8 + l, fm);
    }
    __syncthreads();
    if (act) {
      float a0 = bias, a1 = 0.f, a2 = 0.f, a3 = 0.f;
      const uint4* vq = (const uint4*)sv32;
#pragma unroll
      for (int qq = 0; qq < 34; ++qq) {
        uint4 v = vq[qq];
        a0 = dot2(u2h2(v.x), u2h2(wr[qq * 4 + 0]), a0);
        a1 = dot2(u2h2(v.y), u2h2(wr[qq * 4 + 1]), a1);
        a2 = dot2(u2h2(v.z), u2h2(wr[qq * 4 + 2]), a2);
        a3 = dot2(u2h2(v.w), u2h2(wr[qq * 4 + 3]), a3);
      }
      float a = (a0 + a1) + (a2 + a3);
      a = (a > 0.f) ? a : 0.2f * a;
      float s = wave_sum(a * w2f) + b2f;
      if (l == 0) scores[e] = s;
      wmax = fmaxf(wmax, s);
    }
    __syncthreads();
  }
  if (l == 0) sRed[w] = wmax;
  __syncthreads();
  if (tid == 0)
    pmax[blockIdx.x] = fmaxf(fmaxf(sRed[0], sRed[1]), fmaxf(sRed[2], sRed[3]));
}

__global__ __launch_bounds__(256) void k_msg(
    const _Float16* __restrict__ h, const void* __restrict__ ei,
    const void* __restrict__ ea,
    const void* __restrict__ mw1, const void* __restrict__ mb1,
    const void* __restrict__ mw2, const void* __restrict__ mb2,
    const float* __restrict__ scores, const float* __restrict__ gmaxp,
    float* __restrict__ numer, float* __restrict__ denom,
    const int* __restrict__ flags, int lay) {
  const int fm = flags[0], im = flags[1];
  const int tid = threadIdx.x;
  const int slot = tid >> 7, t = tid & 127;
  __shared__ __align__(16) _Float16 sV[2][HID + EDGE_IN];
  __shared__ __align__(16) _Float16 sM1b[2][HID];
  unsigned int w1[72], w2[64];
  {
    const size_t b1p = (size_t)lay * HID * 72 + (size_t)t * 72;
#pragma unroll
    for (int i = 0; i < 72; ++i) w1[i] = load_pair(mw1, b1p + i, fm);
    const size_t b2p = (size_t)lay * HID * 64 + (size_t)t * 64;
#pragma unroll
    for (int i = 0; i < 64; ++i) w2[i] = load_pair(mw2, b2p + i, fm);
  }
  const float b1 = load_scal(mb1, lay * HID + t, fm);
  const float b2 = load_scal(mb2, lay * HID + t, fm);
  const float gmax = gmaxp[0];
  unsigned int* sv32 = (unsigned int*)sV[slot];
  for (int base = blockIdx.x * 2; base < N_EDGES; base += gridDim.x * 2) {
    const int e = base + slot;
    const int src = load_idx(ei, e, im);
    const int dst = load_idx(ei, N_EDGES + e, im);
    if (t < 64) {
      sv32[t] = ((const unsigned int*)(h + (size_t)src * HID))[t];
    } else if (t < 72) {
      sv32[t] = load_pair(ea, (size_t)e * 8 + (t - 64), fm);
    }
    __syncthreads();
    float a0 = b1, a1 = 0.f, a2 = 0.f, a3 = 0.f;
    const uint4* vq = (const uint4*)sv32;
#pragma unroll
    for (int qq = 0; qq < 18; ++qq) {
      uint4 v = vq[qq];
      a0 = dot2(u2h2(v.x), u2h2(w1[qq * 4 + 0]), a0);
      a1 = dot2(u2h2(v.y), u2h2(w1[qq * 4 + 1]), a1);
      a2 = dot2(u2h2(v.z), u2h2(w1[qq * 4 + 2]), a2);
      a3 = dot2(u2h2(v.w), u2h2(w1[qq * 4 + 3]), a3);
    }
    sM1b[slot][t] = (_Float16)fmaxf((a0 + a1) + (a2 + a3), 0.f);
    __syncthreads();
    float c0 = b2, c1 = 0.f, c2 = 0.f, c3 = 0.f;
    const uint4* mq = (const uint4*)sM1b[slot];
#pragma unroll
    for (int qq = 0; qq < 16; ++qq) {
      uint4 v = mq[qq];
      c0 = dot2(u2h2(v.x), u2h2(w2[qq * 4 + 0]), c0);
      c1 = dot2(u2h2(v.y), u2h2(w2[qq * 4 + 1]), c1);
      c2 = dot2(u2h2(v.z), u2h2(w2[qq * 4 + 2]), c2);
      c3 = dot2(u2h2(v.w), u2h2(w2[qq * 4 + 3]), c3);
    }
    float msg = (c0 + c1) + (c2 + c3);
    float wgt = __expf(scores[e] - gmax);
    atomicAdd(&numer[(size_t)dst * HID + t], msg * wgt);
    if (t == 0) atomicAdd(&denom[dst], wgt);
    __syncthreads();
  }
}

__global__ __launch_bounds__(256) void k_upd(
    _Float16* __restrict__ h, const float* __restrict__ numer,
    const float* __restrict__ denom,
    const void* __restrict__ uw1, const void* __restrict__ ub1,
    const void* __restrict__ uw2, const void* __restrict__ ub2,
    const void* __restrict__ lng, const void* __restrict__ lnb,
    const int* __restrict__ flags, int lay) {
  const int fm = flags[0];
  const int tid = threadIdx.x;
  const int slot = tid >> 7, t = tid & 127;
  const int wv = (tid >> 6) & 1;
  __shared__ __align__(16) _Float16 sV[2][2 * HID];
  __shared__ __align__(16) _Float16 sM1b[2][HID];
  __shared__ float sRed[2][2][2];
  unsigned int w1[128], w2[64];
  {
    const size_t b1p = (size_t)lay * HID * 128 + (size_t)t * 128;
#pragma unroll
    for (int i = 0; i < 128; ++i) w1[i] = load_pair(uw1, b1p + i, fm);
    const size_t b2p = (size_t)lay * HID * 64 + (size_t)t * 64;
#pragma unroll
    for (int i = 0; i < 64; ++i) w2[i] = load_pair(uw2, b2p + i, fm);
  }
  const float b1 = load_scal(ub1, lay * HID + t, fm);
  const float b2 = load_scal(ub2, lay * HID + t, fm);
  const float gg = load_scal(lng, lay * HID + t, fm);
  const float bb = load_scal(lnb, lay * HID + t, fm);
  unsigned int* sv32 = (unsigned int*)sV[slot];
  for (int base = blockIdx.x * 2; base < N_NODES; base += gridDim.x * 2) {
    const int n = base + slot;
    const float inv = 1.f / (denom[n] + 1e-6f);
    if (t < 64) {
      sv32[t] = ((const unsigned int*)(h + (size_t)n * HID))[t];
    } else {
      const int j = (t - 64) * 2;
      h2 p; p.x = (_Float16)(numer[(size_t)n * HID + j] * inv);
      p.y = (_Float16)(numer[(size_t)n * HID + j + 1] * inv);
      union { h2 hh; unsigned int u; } c; c.hh = p;
      sv32[64 + (t - 64)] = c.u;
    }
    __syncthreads();
    float a0 = b1, a1 = 0.f, a2 = 0.f, a3 = 0.f;
    const uint4* vq = (const uint4*)sv32;
#pragma unroll
    for (int qq = 0; qq < 32; ++qq) {
      uint4 v = vq[qq];
      a0 = dot2(u2h2(v.x), u2h2(w1[qq * 4 + 0]), a0);
      a1 = dot2(u2h2(v.y), u2h2(w1[qq * 4 + 1]), a1);
      a2 = dot2(u2h2(v.z), u2h2(w1[qq * 4 + 2]), a2);
      a3 = dot2(u2h2(v.w), u2h2(w1[qq * 4 + 3]), a3);
    }
    sM1b[slot][t] = (_Float16)fmaxf((a0 + a1) + (a2 + a3), 0.f);
    __syncthreads();
    float c0 = b2, c1 = 0.f, c2 = 0.f, c3 = 0.f;
    const uint4* mq = (const uint4*)sM1b[slot];
#pragma unroll
    for (int qq = 0; qq < 16; ++qq) {
      uint4 v = mq[qq];
      c0 = dot2(u2h2(v.x), u2h2(w2[qq * 4 + 0]), c0);
      c1 = dot2(u2h2(v.y), u2h2(w2[qq * 4 + 1]), c1);
      c2 = dot2(u2h2(v.z), u2h2(w2[qq * 4 + 2]), c2);
      c3 = dot2(u2h2(v.w), u2h2(w2[qq * 4 + 3]), c3);
    }
    const float hold = (float)((const _Float16*)sV[slot])[t];
    const float r = fmaxf((c0 + c1) + (c2 + c3) + hold, 0.f);
    float s1 = wave_sum(r);
    float s2 = wave_sum(r * r);
    if ((tid & 63) == 0) { sRed[slot][wv][0] = s1; sRed[slot][wv][1] = s2; }
    __syncthreads();
    const float S1 = sRed[slot][0][0] + sRed[slot][1][0];
    const float S2 = sRed[slot][0][1] + sRed[slot][1][1];
    const float mu = S1 * (1.f / HID);
    const float var = S2 * (1.f / HID) - mu * mu;
    const float rs = rsqrtf(var + 1e-5f);
    h[(size_t)n * HID + t] = (_Float16)((r - mu) * rs * gg + bb);
    __syncthreads();
  }
}

// ---------------- readout ----------------------------------------------------
__global__ __launch_bounds__(256) void k_read(
    const _Float16* __restrict__ h, const void* __restrict__ gctx,
    const void* __restrict__ qw1, const void* __restrict__ qb1,
    const void* __restrict__ qw2, const void* __restrict__ qb2,
    void* __restrict__ out, const int* __restrict__ flags) {
  const int fm = flags[0];
  const int tid = threadIdx.x;
  const int slot = tid >> 7, t = tid & 127;
  const int wv = (tid >> 6) & 1;
  __shared__ __align__(16) _Float16 sV[2][HID];
  __shared__ __align__(16) _Float16 sCtx[GCTX];
  __shared__ float sRed[2][2];
  unsigned int w1[96];
#pragma unroll
  for (int i = 0; i < 96; ++i) w1[i] = load_pair(qw1, (size_t)t * 96 + i, fm);
  const float b1 = load_scal(qb1, t, fm);
  const float w2f = load_scal(qw2, t, fm);
  const float b2 = load_scal(qb2, 0, fm);
  if (tid < GCTX / 2)
    ((unsigned int*)sCtx)[tid] = load_pair(gctx, tid, fm);
  __syncthreads();
  unsigned int* sv32 = (unsigned int*)sV[slot];
  for (int base = blockIdx.x * 2; base < N_NODES; base += gridDim.x * 2) {
    const int n = base + slot;
    if (t < 64) sv32[t] = ((const unsigned int*)(h + (size_t)n * HID))[t];
    __syncthreads();
    float a0 = b1, a1 = 0.f, a2 = 0.f, a3 = 0.f;
    const uint4* vq = (const uint4*)sv32;
#pragma unroll
    for (int qq = 0; qq < 16; ++qq) {
      uint4 v = vq[qq];
      a0 = dot2(u2h2(v.x), u2h2(w1[qq * 4 + 0]), a0);
      a1 = dot2(u2h2(v.y), u2h2(w1[qq * 4 + 1]), a1);
      a2 = dot2(u2h2(v.z), u2h2(w1[qq * 4 + 2]), a2);
      a3 = dot2(u2h2(v.w), u2h2(w1[qq * 4 + 3]), a3);
    }
    const uint4* cq = (const uint4*)sCtx;
#pragma unroll
    for (int qq = 0; qq < 8; ++qq) {
      uint4 v = cq[qq];
      a0 = dot2(u2h2(v.x), u2h2(w1[64 + qq * 4 + 0]), a0);
      a1 = dot2(u2h2(v.y), u2h2(w1[64 + qq * 4 + 1]), a1);
      a2 = dot2(u2h2(v.z), u2h2(w1[64 + qq * 4 + 2]), a2);
      a3 = dot2(u2h2(v.w), u2h2(w1[64 + qq * 4 + 3]), a3);
    }
    float u = fmaxf((a0 + a1) + (a2 + a3), 0.f);
    float s = wave_sum(u * w2f);
    if ((tid & 63) == 0) sRed[slot][wv] = s;
    __syncthreads();
    if (t == 0) {
      const float val = sRed[slot][0] + sRed[slot][1] + b2;
      if (fm == 0) ((__hip_bfloat16*)out)[n] = __float2bfloat16(val);
      else if (fm == 2) ((_Float16*)out)[n] = (_Float16)val;
      else ((float*)out)[n] = val;
    }
    __syncthreads();
  }
}

extern "C" void kernel_launch(void* const* d_in, const int* in_sizes, int n_in,
                              void* d_out, int out_size, void* d_ws, size_t ws_size,
                              hipStream_t stream) {
  const void* x    = d_in[0];
  const void* ei   = d_in[1];
  const void* ea   = d_in[2];
  const void* gctx = d_in[3];
  const void* npw  = d_in[4];
  const void* npb  = d_in[5];
  const void* mw1  = d_in[6];
  const void* mb1  = d_in[7];
  const void* mw2  = d_in[8];
  const void* mb2  = d_in[9];
  const void* aw1  = d_in[10];
  const void* ab1  = d_in[11];
  const void* aw2  = d_in[12];
  const void* ab2  = d_in[13];
  const void* uw1  = d_in[14];
  const void* ub1  = d_in[15];
  const void* uw2  = d_in[16];
  const void* ub2  = d_in[17];
  const void* lng  = d_in[18];
  const void* lnb  = d_in[19];
  const void* qw1  = d_in[20];
  const void* qb1  = d_in[21];
  const void* qw2  = d_in[22];
  const void* qb2  = d_in[23];

  char* ws = (char*)d_ws;
  dim3 blk(256);

  size_t off = 0;
  auto alloc = [&](size_t bytes) {
    void* p = ws + off;
    off = (off + bytes + 255) & ~(size_t)255;
    return p;
  };
  int* flags       = (int*)alloc(8 * 4);
  _Float16* hbuf   = (_Float16*)alloc((size_t)N_NODES * HID * 2);
  float* scores    = (float*)alloc((size_t)N_EDGES * 4);
  float* pmax      = (float*)alloc(2048 * 4);
  float* gmax      = (float*)alloc(4);
  int* cnt         = (int*)alloc((size_t)N_NODES * 4);
  int* cur         = (int*)alloc((size_t)N_NODES * 4);
  int* row_ptr     = (int*)alloc((size_t)(N_NODES + 1) * 4);
  int2* sd2        = (int2*)alloc((size_t)N_EDGES * 8);
  _Float16* eaPerm = (_Float16*)alloc((size_t)N_EDGES * EDGE_IN * 2);
  _Float16* Sbuf   = (_Float16*)alloc((size_t)N_NODES * HID * 2);
  float* Dbuf      = (float*)alloc((size_t)N_NODES * 4);
  _Float16* msgbuf = (_Float16*)alloc((size_t)N_EDGES * HID * 2);
  const size_t need_big = off;

  if (ws_size >= need_big) {
    // ======== MFMA + CSR-ordered path ========
    k_detect<<<1, blk, 0, stream>>>((const unsigned int*)x, (const unsigned int*)ei, flags);
    k_proj<<<1024, blk, 0, stream>>>(x, npw, npb, hbuf, flags);
    hipMemsetAsync(cnt, 0, (size_t)N_NODES * 4, stream);
    k_hist<<<1024, blk, 0, stream>>>(ei, cnt, flags);
    k_scan<<<1, blk, 0, stream>>>(cnt, row_ptr, cur);
    k_scatter<<<1024, blk, 0, stream>>>(ei, ea, cur, sd2, eaPerm, flags);
    for (int lay = 0; lay < NLAYER; ++lay) {
      k_edge<<<1024, blk, 0, stream>>>(hbuf, sd2, eaPerm, aw1, ab1, aw2, ab2,
                                       mw1, mb1, scores, pmax, msgbuf, flags, lay);
      k_rmax<<<1, blk, 0, stream>>>(pmax, 1024, gmax);
      k_gather<<<N_NODES / 16, blk, 0, stream>>>(msgbuf, scores, row_ptr, gmax,
                                                 Sbuf, Dbuf);
      k_upd3<<<1024, blk, 0, stream>>>(hbuf, Sbuf, Dbuf, mw2, mb2,
                                       uw1, ub1, uw2, ub2, lng, lnb, flags, lay);
    }
    k_read<<<1024, blk, 0, stream>>>(hbuf, gctx, qw1, qb1, qw2, qb2, d_out, flags);
  } else {
    // ======== fallback: round-2 passing path ========
    size_t o2 = 0;
    int* flags2 = (int*)(ws + o2); o2 += 256;
    _Float16* hb = (_Float16*)(ws + o2); o2 += (size_t)N_NODES * HID * 2;
    o2 = (o2 + 255) & ~(size_t)255;
    float* sc = (float*)(ws + o2); o2 += (size_t)N_EDGES * 4;
    float* pm = (float*)(ws + o2); o2 += 1024 * 4;
    float* gm = (float*)(ws + o2); o2 += 256;
    float* numer = (float*)(ws + o2); o2 += (size_t)N_NODES * HID * 4;
    float* denom = (float*)(ws + o2); o2 += (size_t)N_NODES * 4;
    k_detect<<<1, blk, 0, stream>>>((const unsigned int*)x, (const unsigned int*)ei, flags2);
    k_proj<<<1024, blk, 0, stream>>>(x, npw, npb, hb, flags2);
    for (int lay = 0; lay < NLAYER; ++lay) {
      hipMemsetAsync(numer, 0, (size_t)N_NODES * HID * 4, stream);
      hipMemsetAsync(denom, 0, (size_t)N_NODES * 4, stream);
      k_attn<<<1024, blk, 0, stream>>>(hb, ei, ea, aw1, ab1, aw2, ab2, sc, pm,
                                       flags2, lay);
      k_rmax<<<1, blk, 0, stream>>>(pm, 1024, gm);
      k_msg<<<1024, blk, 0, stream>>>(hb, ei, ea, mw1, mb1, mw2, mb2, sc, gm,
                                      numer, denom, flags2, lay);
      k_upd<<<1024, blk, 0, stream>>>(hb, numer, denom, uw1, ub1, uw2, ub2, lng, lnb,
                                      flags2, lay);
    }
    k_read<<<1024, blk, 0, stream>>>(hb, gctx, qw1, qb1, qw2, qb2, d_out, flags2);
  }
}

// Round 11
// 838.377 us; speedup vs baseline: 2.0988x; 1.2282x over previous
//
#include <hip/hip_runtime.h>
#include <hip/hip_bf16.h>

#define N_NODES 50000
#define N_EDGES 600000
#define NODE_IN 32
#define EDGE_IN 16
#define HID 128
#define NLAYER 3
#define GCTX 64

typedef _Float16 h2 __attribute__((ext_vector_type(2)));
typedef _Float16 f16x8 __attribute__((ext_vector_type(8)));
typedef float f32x4 __attribute__((ext_vector_type(4)));

__device__ __forceinline__ float bf2f(unsigned short u) {
  union { unsigned int i; float f; } c; c.i = ((unsigned int)u) << 16; return c.f;
}
__device__ __forceinline__ unsigned int bfp2hp(unsigned int b) {
  union { unsigned int i; float f; } lo, hi;
  lo.i = b << 16; hi.i = b & 0xffff0000u;
  h2 r; r.x = (_Float16)lo.f; r.y = (_Float16)hi.f;
  union { h2 h; unsigned int u; } c; c.h = r; return c.u;
}
__device__ __forceinline__ h2 u2h2(unsigned int u) {
  union { unsigned int u; h2 h; } c; c.u = u; return c.h;
}
__device__ __forceinline__ float dot2(h2 a, h2 b, float c) {
#if __has_builtin(__builtin_amdgcn_fdot2)
  return __builtin_amdgcn_fdot2(a, b, c, false);
#else
  return c + (float)a.x * (float)b.x + (float)a.y * (float)b.y;
#endif
}

// generic loaders: fm 0=bf16, 1=fp32, 2=fp16
__device__ __forceinline__ unsigned int load_pair(const void* p, size_t pairIdx, int fm) {
  if (fm == 0) return bfp2hp(((const unsigned int*)p)[pairIdx]);
  if (fm == 2) return ((const unsigned int*)p)[pairIdx];
  const float* f = (const float*)p;
  h2 r; r.x = (_Float16)f[2 * pairIdx]; r.y = (_Float16)f[2 * pairIdx + 1];
  union { h2 h; unsigned int u; } c; c.h = r; return c.u;
}
__device__ __forceinline__ float load_scal(const void* p, size_t idx, int fm) {
  if (fm == 0) return bf2f(((const unsigned short*)p)[idx]);
  if (fm == 2) return (float)((const _Float16*)p)[idx];
  return ((const float*)p)[idx];
}
__device__ __forceinline__ int load_idx(const void* p, size_t pos, int im) {
  if (im == 0) return ((const int*)p)[pos];
  return (int)((const long long*)p)[pos];
}
__device__ __forceinline__ uint4 zero4() { uint4 z; z.x = z.y = z.z = z.w = 0u; return z; }
__device__ __forceinline__ uint4 load8(const void* p, size_t eoff, int fm) {
  uint4 r;
  if (fm == 0) {
    uint4 t = *(const uint4*)((const unsigned short*)p + eoff);
    r.x = bfp2hp(t.x); r.y = bfp2hp(t.y); r.z = bfp2hp(t.z); r.w = bfp2hp(t.w);
  } else if (fm == 2) {
    r = *(const uint4*)((const unsigned short*)p + eoff);
  } else {
    const float* f = (const float*)p + eoff;
    h2 a, b, c, d;
    a.x = (_Float16)f[0]; a.y = (_Float16)f[1];
    b.x = (_Float16)f[2]; b.y = (_Float16)f[3];
    c.x = (_Float16)f[4]; c.y = (_Float16)f[5];
    d.x = (_Float16)f[6]; d.y = (_Float16)f[7];
    union { h2 h; unsigned int u; } ua, ub, uc, ud;
    ua.h = a; ub.h = b; uc.h = c; ud.h = d;
    r.x = ua.u; r.y = ub.u; r.z = uc.u; r.w = ud.u;
  }
  return r;
}
__device__ __forceinline__ f32x4 mfma16(uint4 a, uint4 b, f32x4 c) {
  union { uint4 u; f16x8 h; } A, B; A.u = a; B.u = b;
  return __builtin_amdgcn_mfma_f32_16x16x32_f16(A.h, B.h, c, 0, 0, 0);
}

__device__ __forceinline__ float wave_sum(float v) {
  for (int m = 32; m >= 1; m >>= 1) v += __shfl_xor(v, m, 64);
  return v;
}
__device__ __forceinline__ int wave_sum_i(int v) {
  for (int m = 32; m >= 1; m >>= 1) v += __shfl_xor(v, m, 64);
  return v;
}
__device__ __forceinline__ float wave_max(float v) {
  for (int m = 32; m >= 1; m >>= 1) v = fmaxf(v, __shfl_xor(v, m, 64));
  return v;
}

// ---------------- dtype detector -------------------------------------------
__global__ __launch_bounds__(256) void k_detect(const unsigned int* __restrict__ x,
                                                const unsigned int* __restrict__ ei,
                                                int* __restrict__ flags) {
  __shared__ int sIn, sOddNZ;
  const int tid = threadIdx.x;
  if (tid == 0) { sIn = 0; sOddNZ = 0; }
  __syncthreads();
  int cnt = 0;
  for (int i = tid; i < 2048; i += 256) {
    unsigned int d = x[i];
    float v0 = fabsf(bf2f((unsigned short)(d & 0xffff)));
    float v1 = fabsf(bf2f((unsigned short)(d >> 16)));
    if (v0 >= 0.1f && v0 <= 6.0f) cnt++;
    if (v1 >= 0.1f && v1 <= 6.0f) cnt++;
  }
  int nz = 0;
  for (int i = tid; i < 512; i += 256)
    if (ei[2 * i + 1] != 0) nz++;
  atomicAdd(&sIn, cnt);
  atomicAdd(&sOddNZ, nz);
  __syncthreads();
  if (tid == 0) {
    float frac = (float)sIn / 4096.f;
    flags[0] = (frac > 0.75f) ? 0 : ((frac >= 0.3f) ? 1 : 2);
    flags[1] = (sOddNZ < 4) ? 1 : 0;  // 1 => int64 edge_index
  }
}

// ---------------- node projection ------------------------------------------
__global__ __launch_bounds__(256) void k_proj(
    const void* __restrict__ x, const void* __restrict__ W,
    const void* __restrict__ b, _Float16* __restrict__ h,
    const int* __restrict__ flags) {
  const int fm = flags[0];
  const int tid = threadIdx.x;
  const int slot = tid >> 7;
  const int t = tid & 127;
  __shared__ __align__(16) _Float16 sX[2][NODE_IN];
  unsigned int w[16];
#pragma unroll
  for (int i = 0; i < 16; ++i) w[i] = load_pair(W, (size_t)t * 16 + i, fm);
  const float bias = load_scal(b, t, fm);
  unsigned int* sx32 = (unsigned int*)sX[slot];
  for (int base = blockIdx.x * 2; base < N_NODES; base += gridDim.x * 2) {
    const int n = base + slot;
    if (t < 16) sx32[t] = load_pair(x, (size_t)n * 16 + t, fm);
    __syncthreads();
    float a0 = bias, a1 = 0.f, a2 = 0.f, a3 = 0.f;
    const uint4* vq = (const uint4*)sx32;
#pragma unroll
    for (int q = 0; q < 4; ++q) {
      uint4 v = vq[q];
      a0 = dot2(u2h2(v.x), u2h2(w[q * 4 + 0]), a0);
      a1 = dot2(u2h2(v.y), u2h2(w[q * 4 + 1]), a1);
      a2 = dot2(u2h2(v.z), u2h2(w[q * 4 + 2]), a2);
      a3 = dot2(u2h2(v.w), u2h2(w[q * 4 + 3]), a3);
    }
    h[(size_t)n * HID + t] = (_Float16)fmaxf((a0 + a1) + (a2 + a3), 0.f);
    __syncthreads();
  }
}

// ---------------- CSR build (parallel) --------------------------------------
__global__ __launch_bounds__(256) void k_hist(const void* __restrict__ ei,
                                              int* __restrict__ cnt,
                                              const int* __restrict__ flags) {
  const int im = flags[1];
  for (int e = blockIdx.x * 256 + threadIdx.x; e < N_EDGES; e += gridDim.x * 256)
    atomicAdd(&cnt[load_idx(ei, N_EDGES + e, im)], 1);
}
// 256 blocks: block b sums its 196-node chunk of cnt
__global__ __launch_bounds__(256) void k_psum(const int* __restrict__ cnt,
                                              int* __restrict__ csum) {
  const int b = blockIdx.x;
  const int c0 = b * 196;
  const int c1 = (c0 + 196 < N_NODES) ? c0 + 196 : N_NODES;
  int s = 0;
  for (int i = c0 + threadIdx.x; i < c1; i += 256) s += cnt[i];
  s = wave_sum_i(s);
  __shared__ int sm[4];
  if ((threadIdx.x & 63) == 0) sm[threadIdx.x >> 6] = s;
  __syncthreads();
  if (threadIdx.x == 0) csum[b] = sm[0] + sm[1] + sm[2] + sm[3];
}
// 256 blocks: block b computes exclusive prefix of csum, fills its chunk
__global__ __launch_bounds__(256) void k_fill(const int* __restrict__ cnt,
                                              const int* __restrict__ csum,
                                              int* __restrict__ row_ptr,
                                              int* __restrict__ cur) {
  const int b = blockIdx.x;
  const int tid = threadIdx.x;
  const int c0 = b * 196;
  const int c1 = (c0 + 196 < N_NODES) ? c0 + 196 : N_NODES;
  __shared__ int sCnt[196];
  __shared__ int sm[4];
  int v = (tid < b) ? csum[tid] : 0;
  v = wave_sum_i(v);
  if ((tid & 63) == 0) sm[tid >> 6] = v;
  for (int i = c0 + tid; i < c1; i += 256) sCnt[i - c0] = cnt[i];
  __syncthreads();
  if (tid == 0) {
    int off = sm[0] + sm[1] + sm[2] + sm[3];
    for (int i = c0; i < c1; ++i) {
      row_ptr[i] = off; cur[i] = off; off += sCnt[i - c0];
    }
    if (b == 255) row_ptr[N_NODES] = off;
  }
}
__global__ __launch_bounds__(256) void k_scatter(const void* __restrict__ ei,
                                                 const void* __restrict__ ea,
                                                 int* __restrict__ cur,
                                                 int2* __restrict__ sd2,
                                                 _Float16* __restrict__ eaPerm,
                                                 const int* __restrict__ flags) {
  const int im = flags[1], fm = flags[0];
  for (int e = blockIdx.x * 256 + threadIdx.x; e < N_EDGES; e += gridDim.x * 256) {
    const int s = load_idx(ei, e, im);
    const int d = load_idx(ei, N_EDGES + e, im);
    const int pos = atomicAdd(&cur[d], 1);
    int2 sd; sd.x = s; sd.y = d;
    sd2[pos] = sd;
    uint4 lo = load8(ea, (size_t)e * 16, fm);
    uint4 hi = load8(ea, (size_t)e * 16 + 8, fm);
    *(uint4*)(eaPerm + (size_t)pos * 16) = lo;
    *(uint4*)(eaPerm + (size_t)pos * 16 + 8) = hi;
  }
}

// ====== MFMA fused edge kernel, CSR order, 32-edge tiles, m1 output =========
#define SAP 296
#define SM1P 136
#define NT32 (N_EDGES / 32)

__global__ __launch_bounds__(256) void k_edge(
    const _Float16* __restrict__ h, const int2* __restrict__ sd2,
    const _Float16* __restrict__ eaPerm,
    const void* __restrict__ aw1, const void* __restrict__ ab1,
    const void* __restrict__ aw2, const void* __restrict__ ab2,
    const void* __restrict__ mw1, const void* __restrict__ mb1,
    float* __restrict__ scores, float* __restrict__ pmax,
    _Float16* __restrict__ msgbuf, const int* __restrict__ flags, int lay) {
  const int fm = flags[0];
  const int tid = threadIdx.x;
  const int w = tid >> 6, l = tid & 63;
  const int m16 = l & 15, q = l >> 4;
  __shared__ __align__(16) _Float16 sA[2][32 * SAP];
  __shared__ float sS[2][4][32];

  uint4 bA[9], bM1[2][5];
  {
    const int arow = w * 16 + m16;
    const size_t awb = (size_t)lay * 64 * 272 + (size_t)arow * 272;
#pragma unroll
    for (int ks = 0; ks < 9; ++ks) {
      const int c0 = ks * 32 + q * 8;
      bA[ks] = (c0 < 272) ? load8(aw1, awb + c0, fm) : zero4();
    }
#pragma unroll
    for (int nt = 0; nt < 2; ++nt) {
      const int mrow = (2 * w + nt) * 16 + m16;
      const size_t m1b = (size_t)lay * 128 * 144 + (size_t)mrow * 144;
#pragma unroll
      for (int ks = 0; ks < 5; ++ks) {
        const int c0 = ks * 32 + q * 8;
        bM1[nt][ks] = (c0 < 144) ? load8(mw1, m1b + c0, fm) : zero4();
      }
    }
  }
  const float ab1v = load_scal(ab1, lay * 64 + w * 16 + m16, fm);
  const float w2s  = load_scal(aw2, lay * 64 + w * 16 + m16, fm);
  const float b2f  = load_scal(ab2, lay, fm);
  float b1v[2];
#pragma unroll
  for (int nt = 0; nt < 2; ++nt)
    b1v[nt] = load_scal(mb1, lay * 128 + (2 * w + nt) * 16 + m16, fm);

  const int ide0 = tid >> 4, ch = tid & 15, ide1 = ide0 + 16;
  float lmax = -3.4e38f;
  uint4 rHs0, rHd0, rHs1, rHd1, rEa;
  const int G = gridDim.x;
  int t = blockIdx.x, pt = -1, buf = 0;

  if (tid < 128) {
    const int b = tid >> 6, s = tid & 63;
    *(uint4*)(sA[b] + (s >> 1) * SAP + 272 + (s & 1) * 8) = zero4();
  }
  {  // prologue prefetch
    const int e0 = t * 32;
    const int2 s0 = sd2[e0 + ide0], s1 = sd2[e0 + ide1];
    rHs0 = *(const uint4*)(h + (size_t)s0.x * HID + ch * 8);
    rHd0 = *(const uint4*)(h + (size_t)s0.y * HID + ch * 8);
    rHs1 = *(const uint4*)(h + (size_t)s1.x * HID + ch * 8);
    rHd1 = *(const uint4*)(h + (size_t)s1.y * HID + ch * 8);
    if (tid < 64)
      rEa = *(const uint4*)(eaPerm + (size_t)(e0 + (tid >> 1)) * 16 + (tid & 1) * 8);
  }
  __syncthreads();

  while (t < NT32) {
    _Float16* A = sA[buf];
    *(uint4*)(A + ide0 * SAP + ch * 8) = rHs0;
    *(uint4*)(A + ide0 * SAP + 128 + ch * 8) = rHd0;
    *(uint4*)(A + ide1 * SAP + ch * 8) = rHs1;
    *(uint4*)(A + ide1 * SAP + 128 + ch * 8) = rHd1;
    if (tid < 64)
      *(uint4*)(A + (tid >> 1) * SAP + 256 + (tid & 1) * 8) = rEa;
    __syncthreads();
    const int nxt = t + G;
    if (nxt < NT32) {
      const int e0 = nxt * 32;
      const int2 s0 = sd2[e0 + ide0], s1 = sd2[e0 + ide1];
      rHs0 = *(const uint4*)(h + (size_t)s0.x * HID + ch * 8);
      rHd0 = *(const uint4*)(h + (size_t)s0.y * HID + ch * 8);
      rHs1 = *(const uint4*)(h + (size_t)s1.x * HID + ch * 8);
      rHd1 = *(const uint4*)(h + (size_t)s1.y * HID + ch * 8);
      if (tid < 64)
        rEa = *(const uint4*)(eaPerm + (size_t)(e0 + (tid >> 1)) * 16 + (tid & 1) * 8);
    }
#pragma unroll
    for (int mg = 0; mg < 2; ++mg) {
      const int arow = m16 + 16 * mg;
      uint4 aF[9];
#pragma unroll
      for (int ks = 0; ks < 9; ++ks)
        aF[ks] = *(const uint4*)(A + arow * SAP + ks * 32 + q * 8);
      {
        f32x4 aacc = {0.f, 0.f, 0.f, 0.f};
#pragma unroll
        for (int ks = 0; ks < 9; ++ks) aacc = mfma16(aF[ks], bA[ks], aacc);
        float sv[4];
#pragma unroll
        for (int r = 0; r < 4; ++r) {
          float v = aacc[r] + ab1v;
          v = (v > 0.f) ? v : 0.2f * v;  // leaky_relu(0.2)
          sv[r] = v * w2s;
        }
#pragma unroll
        for (int mk = 1; mk <= 8; mk <<= 1) {
#pragma unroll
          for (int r = 0; r < 4; ++r) sv[r] += __shfl_xor(sv[r], mk, 64);
        }
        if (m16 == 0)
          *(float4*)(&sS[buf][w][mg * 16 + q * 4]) = make_float4(sv[0], sv[1], sv[2], sv[3]);
      }
#pragma unroll
      for (int nt = 0; nt < 2; ++nt) {
        f32x4 macc = {0.f, 0.f, 0.f, 0.f};
#pragma unroll
        for (int ks = 0; ks < 4; ++ks) macc = mfma16(aF[ks], bM1[nt][ks], macc);
        macc = mfma16(aF[8], bM1[nt][4], macc);
        const int col = (2 * w + nt) * 16 + m16;
#pragma unroll
        for (int r = 0; r < 4; ++r)
          msgbuf[(size_t)(t * 32 + mg * 16 + q * 4 + r) * HID + col] =
              (_Float16)fmaxf(macc[r] + b1v[nt], 0.f);
      }
    }
    if (pt >= 0 && tid < 32) {
      const float s = sS[buf ^ 1][0][tid] + sS[buf ^ 1][1][tid] +
                      sS[buf ^ 1][2][tid] + sS[buf ^ 1][3][tid] + b2f;
      scores[pt * 32 + tid] = s;
      lmax = fmaxf(lmax, s);
    }
    pt = t; t = nxt; buf ^= 1;
  }
  __syncthreads();
  if (pt >= 0 && tid < 32) {
    const float s = sS[buf ^ 1][0][tid] + sS[buf ^ 1][1][tid] +
                    sS[buf ^ 1][2][tid] + sS[buf ^ 1][3][tid] + b2f;
    scores[pt * 32 + tid] = s;
    lmax = fmaxf(lmax, s);
  }
  if (w == 0) {
    float m = wave_max((l < 32) ? lmax : -3.4e38f);
    if (tid == 0) pmax[blockIdx.x] = m;
  }
}

// ---------------- global max reduce -----------------------------------------
__global__ __launch_bounds__(256) void k_rmax(const float* __restrict__ pmax, int n,
                                              float* __restrict__ gmax) {
  float m = -3.4e38f;
  for (int i = threadIdx.x; i < n; i += 256) m = fmaxf(m, pmax[i]);
  m = wave_max(m);
  __shared__ float sm[4];
  if ((threadIdx.x & 63) == 0) sm[threadIdx.x >> 6] = m;
  __syncthreads();
  if (threadIdx.x == 0) gmax[0] = fmaxf(fmaxf(sm[0], sm[1]), fmaxf(sm[2], sm[3]));
}

// ============ weight-free streaming gather: S = Σ w·m1, D = Σ w ==============
__global__ __launch_bounds__(256) void k_gather(
    const _Float16* __restrict__ msgbuf, const float* __restrict__ scores,
    const int* __restrict__ row_ptr, const float* __restrict__ gmax,
    _Float16* __restrict__ Sbuf, float* __restrict__ Dbuf) {
  const int w = threadIdx.x >> 6, l = threadIdx.x & 63;
  const int n0 = blockIdx.x * 16;
  const float M = gmax[0];
  const unsigned int* mb32 = (const unsigned int*)msgbuf;
#pragma unroll
  for (int k = 0; k < 4; ++k) {
    const int n = n0 + 4 * w + k;
    const int rp0 = row_ptr[n], rp1 = row_ptr[n + 1];
    float ax0 = 0.f, ay0 = 0.f, d0s = 0.f;
    float ax1 = 0.f, ay1 = 0.f, d1s = 0.f;
    float ax2 = 0.f, ay2 = 0.f, d2s = 0.f;
    float ax3 = 0.f, ay3 = 0.f, d3s = 0.f;
    int i = rp0;
    for (; i + 4 <= rp1; i += 4) {
      const float s0 = scores[i], s1 = scores[i + 1];
      const float s2 = scores[i + 2], s3 = scores[i + 3];
      const unsigned int m0 = mb32[(size_t)i * 64 + l];
      const unsigned int m1 = mb32[(size_t)(i + 1) * 64 + l];
      const unsigned int m2 = mb32[(size_t)(i + 2) * 64 + l];
      const unsigned int m3 = mb32[(size_t)(i + 3) * 64 + l];
      const float w0 = __expf(s0 - M), w1 = __expf(s1 - M);
      const float w2 = __expf(s2 - M), w3 = __expf(s3 - M);
      h2 p0 = u2h2(m0), p1 = u2h2(m1), p2 = u2h2(m2), p3 = u2h2(m3);
      ax0 += w0 * (float)p0.x; ay0 += w0 * (float)p0.y; d0s += w0;
      ax1 += w1 * (float)p1.x; ay1 += w1 * (float)p1.y; d1s += w1;
      ax2 += w2 * (float)p2.x; ay2 += w2 * (float)p2.y; d2s += w2;
      ax3 += w3 * (float)p3.x; ay3 += w3 * (float)p3.y; d3s += w3;
    }
    for (; i < rp1; ++i) {
      const float w0 = __expf(scores[i] - M);
      h2 p0 = u2h2(mb32[(size_t)i * 64 + l]);
      ax0 += w0 * (float)p0.x; ay0 += w0 * (float)p0.y; d0s += w0;
    }
    const float ax = (ax0 + ax1) + (ax2 + ax3);
    const float ay = (ay0 + ay1) + (ay2 + ay3);
    const float den = (d0s + d1s) + (d2s + d3s);
    h2 o; o.x = (_Float16)ax; o.y = (_Float16)ay;
    union { h2 hh; unsigned int u; } c; c.hh = o;
    ((unsigned int*)Sbuf)[(size_t)n * 64 + l] = c.u;
    if (l == 0) Dbuf[n] = den;
  }
}

// ===== dense per-node: agg=(mw2@S+b2·D)/(D+eps) → update MLP → LN ===========
#define SUP3 392
#define SOP 132
__global__ __launch_bounds__(256, 1) void k_upd3(
    _Float16* __restrict__ h, const _Float16* __restrict__ Sbuf,
    const float* __restrict__ Dbuf,
    const void* __restrict__ mw2, const void* __restrict__ mb2,
    const void* __restrict__ uw1, const void* __restrict__ ub1,
    const void* __restrict__ uw2, const void* __restrict__ ub2,
    const void* __restrict__ lng, const void* __restrict__ lnb,
    const int* __restrict__ flags, int lay) {
  const int fm = flags[0];
  const int tid = threadIdx.x;
  const int w = tid >> 6, l = tid & 63;
  const int m16 = l & 15, q = l >> 4;
  __shared__ __align__(16) _Float16 sU[16 * SUP3];
  __shared__ __align__(16) _Float16 sM1[16 * SM1P];
  __shared__ __align__(16) float sO[16 * SOP];
  __shared__ float sD[16];

  uint4 bU1[2][8], bU2[2][4], bM2g[2][4];
  float b1v[2], b2v[2], b2m[2];
#pragma unroll
  for (int nt = 0; nt < 2; ++nt) {
    const int row = w * 32 + nt * 16 + m16;
    const size_t b1p = (size_t)lay * 128 * 256 + (size_t)row * 256;
#pragma unroll
    for (int ks = 0; ks < 8; ++ks) bU1[nt][ks] = load8(uw1, b1p + ks * 32 + q * 8, fm);
    const size_t b2p = (size_t)lay * 128 * 128 + (size_t)row * 128;
#pragma unroll
    for (int ks = 0; ks < 4; ++ks) bU2[nt][ks] = load8(uw2, b2p + ks * 32 + q * 8, fm);
#pragma unroll
    for (int ks = 0; ks < 4; ++ks) bM2g[nt][ks] = load8(mw2, b2p + ks * 32 + q * 8, fm);
    b1v[nt] = load_scal(ub1, lay * 128 + row, fm);
    b2v[nt] = load_scal(ub2, lay * 128 + row, fm);
    b2m[nt] = load_scal(mb2, lay * 128 + row, fm);
  }
  const int nd = tid >> 4, sc = tid & 15;
  float g8[8], be8[8];
#pragma unroll
  for (int j = 0; j < 8; ++j) {
    g8[j] = load_scal(lng, lay * 128 + sc * 8 + j, fm);
    be8[j] = load_scal(lnb, lay * 128 + sc * 8 + j, fm);
  }

  for (int n0 = blockIdx.x * 16; n0 < N_NODES; n0 += gridDim.x * 16) {
    *(uint4*)(sU + nd * SUP3 + sc * 8) =
        *(const uint4*)(h + (size_t)(n0 + nd) * HID + sc * 8);
    *(uint4*)(sU + nd * SUP3 + 128 + sc * 8) =
        *(const uint4*)(Sbuf + (size_t)(n0 + nd) * HID + sc * 8);
    if (tid < 16) sD[tid] = Dbuf[n0 + tid];
    __syncthreads();
    {
      uint4 aS[4];
#pragma unroll
      for (int ks = 0; ks < 4; ++ks)
        aS[ks] = *(const uint4*)(sU + m16 * SUP3 + 128 + ks * 32 + q * 8);
#pragma unroll
      for (int nt = 0; nt < 2; ++nt) {
        f32x4 acc = {0.f, 0.f, 0.f, 0.f};
#pragma unroll
        for (int ks = 0; ks < 4; ++ks) acc = mfma16(aS[ks], bM2g[nt][ks], acc);
        const int colw = w * 32 + nt * 16 + m16;
#pragma unroll
        for (int r = 0; r < 4; ++r) {
          const int row = q * 4 + r;
          const float Dv = sD[row];
          const float inv = 1.f / (Dv + 1e-6f);
          sU[row * SUP3 + 256 + colw] = (_Float16)((acc[r] + b2m[nt] * Dv) * inv);
        }
      }
    }
    __syncthreads();
    uint4 aF[8];
#pragma unroll
    for (int ks = 0; ks < 4; ++ks)
      aF[ks] = *(const uint4*)(sU + m16 * SUP3 + ks * 32 + q * 8);
#pragma unroll
    for (int ks = 4; ks < 8; ++ks)
      aF[ks] = *(const uint4*)(sU + m16 * SUP3 + 256 + (ks - 4) * 32 + q * 8);
#pragma unroll
    for (int nt = 0; nt < 2; ++nt) {
      f32x4 acc = {0.f, 0.f, 0.f, 0.f};
#pragma unroll
      for (int ks = 0; ks < 8; ++ks) acc = mfma16(aF[ks], bU1[nt][ks], acc);
      const int colw = w * 32 + nt * 16 + m16;
#pragma unroll
      for (int r = 0; r < 4; ++r)
        sM1[(q * 4 + r) * SM1P + colw] = (_Float16)fmaxf(acc[r] + b1v[nt], 0.f);
    }
    __syncthreads();
    uint4 a2F[4];
#pragma unroll
    for (int ks = 0; ks < 4; ++ks)
      a2F[ks] = *(const uint4*)(sM1 + m16 * SM1P + ks * 32 + q * 8);
#pragma unroll
    for (int nt = 0; nt < 2; ++nt) {
      f32x4 acc = {0.f, 0.f, 0.f, 0.f};
#pragma unroll
      for (int ks = 0; ks < 4; ++ks) acc = mfma16(a2F[ks], bU2[nt][ks], acc);
      const int colw = w * 32 + nt * 16 + m16;
#pragma unroll
      for (int r = 0; r < 4; ++r) {
        const int row = q * 4 + r;
        const float hres = (float)sU[row * SUP3 + colw];
        sO[row * SOP + colw] = fmaxf(acc[r] + b2v[nt] + hres, 0.f);
      }
    }
    __syncthreads();
    float v[8], s1 = 0.f, s2 = 0.f;
    const float4 p0 = *(const float4*)(sO + nd * SOP + sc * 8);
    const float4 p1 = *(const float4*)(sO + nd * SOP + sc * 8 + 4);
    v[0] = p0.x; v[1] = p0.y; v[2] = p0.z; v[3] = p0.w;
    v[4] = p1.x; v[5] = p1.y; v[6] = p1.z; v[7] = p1.w;
#pragma unroll
    for (int j = 0; j < 8; ++j) { s1 += v[j]; s2 += v[j] * v[j]; }
#pragma unroll
    for (int mk = 1; mk <= 8; mk <<= 1) {
      s1 += __shfl_xor(s1, mk, 64);
      s2 += __shfl_xor(s2, mk, 64);
    }
    const float mu = s1 * (1.f / HID);
    const float var = s2 * (1.f / HID) - mu * mu;
    const float rs = rsqrtf(var + 1e-5f);
    unsigned int pk[4];
#pragma unroll
    for (int jj = 0; jj < 4; ++jj) {
      h2 o;
      o.x = (_Float16)((v[2 * jj] - mu) * rs * g8[2 * jj] + be8[2 * jj]);
      o.y = (_Float16)((v[2 * jj + 1] - mu) * rs * g8[2 * jj + 1] + be8[2 * jj + 1]);
      union { h2 hh; unsigned int u; } c; c.hh = o;
      pk[jj] = c.u;
    }
    uint4 outv; outv.x = pk[0]; outv.y = pk[1]; outv.z = pk[2]; outv.w = pk[3];
    *(uint4*)(h + (size_t)(n0 + nd) * HID + sc * 8) = outv;
    __syncthreads();
  }
}

// ===== MFMA readout: ctx folded into cvec; 16 nodes/block ====================
#define SRP 136
__global__ __launch_bounds__(256) void k_read2(
    const _Float16* __restrict__ h, const void* __restrict__ gctx,
    const void* __restrict__ qw1, const void* __restrict__ qb1,
    const void* __restrict__ qw2, const void* __restrict__ qb2,
    void* __restrict__ out, const int* __restrict__ flags) {
  const int fm = flags[0];
  const int tid = threadIdx.x;
  const int w = tid >> 6, l = tid & 63;
  const int m16 = l & 15, q = l >> 4;
  __shared__ __align__(16) _Float16 sU[16 * SRP];
  __shared__ __align__(16) _Float16 sM1[16 * SM1P];
  __shared__ float sCvec[128];

  uint4 bQ[2][4];
#pragma unroll
  for (int nt = 0; nt < 2; ++nt) {
    const int row = w * 32 + nt * 16 + m16;
#pragma unroll
    for (int ks = 0; ks < 4; ++ks)
      bQ[nt][ks] = load8(qw1, (size_t)row * 192 + ks * 32 + q * 8, fm);
  }
  if (tid < 128) {
    float acc = load_scal(qb1, tid, fm);
    for (int j = 0; j < GCTX / 2; ++j) {
      h2 wv = u2h2(load_pair(qw1, (size_t)tid * 96 + 64 + j, fm));
      h2 cv = u2h2(load_pair(gctx, j, fm));
      acc = dot2(cv, wv, acc);
    }
    sCvec[tid] = acc;
  }
  const int nd = tid >> 4, sc = tid & 15;
  float q2[8];
#pragma unroll
  for (int j = 0; j < 8; ++j) q2[j] = load_scal(qw2, sc * 8 + j, fm);
  const float qb2v = load_scal(qb2, 0, fm);
  __syncthreads();

  for (int n0 = blockIdx.x * 16; n0 < N_NODES; n0 += gridDim.x * 16) {
    *(uint4*)(sU + nd * SRP + sc * 8) =
        *(const uint4*)(h + (size_t)(n0 + nd) * HID + sc * 8);
    __syncthreads();
    uint4 aF[4];
#pragma unroll
    for (int ks = 0; ks < 4; ++ks)
      aF[ks] = *(const uint4*)(sU + m16 * SRP + ks * 32 + q * 8);
#pragma unroll
    for (int nt = 0; nt < 2; ++nt) {
      f32x4 acc = {0.f, 0.f, 0.f, 0.f};
#pragma unroll
      for (int ks = 0; ks < 4; ++ks) acc = mfma16(aF[ks], bQ[nt][ks], acc);
      const int colw = w * 32 + nt * 16 + m16;
#pragma unroll
      for (int r = 0; r < 4; ++r)
        sM1[(q * 4 + r) * SM1P + colw] = (_Float16)fmaxf(acc[r] + sCvec[colw], 0.f);
    }
    __syncthreads();
    float s = 0.f;
#pragma unroll
    for (int j = 0; j < 8; ++j)
      s += (float)sM1[nd * SM1P + sc * 8 + j] * q2[j];
#pragma unroll
    for (int mk = 1; mk <= 8; mk <<= 1) s += __shfl_xor(s, mk, 64);
    if (sc == 0) {
      const float val = s + qb2v;
      const int n = n0 + nd;
      if (fm == 0) ((__hip_bfloat16*)out)[n] = __float2bfloat16(val);
      else if (fm == 2) ((_Float16*)out)[n] = (_Float16)val;
      else ((float*)out)[n] = val;
    }
    __syncthreads();
  }
}

// ============ fallback (round-2 passing) kernels ============================
__global__ __launch_bounds__(256) void k_attn(
    const _Float16* __restrict__ h, const void* __restrict__ ei,
    const void* __restrict__ ea,
    const void* __restrict__ aw1, const void* __restrict__ ab1,
    const void* __restrict__ aw2, const void* __restrict__ ab2,
    float* __restrict__ scores, float* __restrict__ pmax,
    const int* __restrict__ flags, int lay) {
  const int fm = flags[0], im = flags[1];
  const int tid = threadIdx.x;
  const int w = tid >> 6, l = tid & 63;
  __shared__ __align__(16) _Float16 sV[4][2 * HID + EDGE_IN];
  __shared__ float sRed[4];
  unsigned int wr[136];
  {
    const size_t base = (size_t)lay * 64 * 136 + (size_t)l * 136;
#pragma unroll
    for (int i = 0; i < 136; ++i) wr[i] = load_pair(aw1, base + i, fm);
  }
  const float bias = load_scal(ab1, lay * 64 + l, fm);
  const float w2f = load_scal(aw2, lay * 64 + l, fm);
  const float b2f = load_scal(ab2, lay, fm);
  float wmax = -3.4e38f;
  unsigned int* sv32 = (unsigned int*)sV[w];
  const int stride = gridDim.x * 4;
  const int nIter = (N_EDGES + stride - 1) / stride;
  for (int it = 0; it < nIter; ++it) {
    const int e = blockIdx.x * 4 + w + it * stride;
    const bool act = (e < N_EDGES);
    if (act) {
      const int src = load_idx(ei, e, im);
      const int dst = load_idx(ei, N_EDGES + e, im);
      sv32[l] = ((const unsigned int*)(h + (size_t)src * HID))[l];
      sv32[64 + l] = ((const unsigned int*)(h + (size_t)dst * HID))[l];
      if (l < 8) sv32[128 + l] = load_pair(ea, (size_t)e * 8 + l, fm);
    }
    __syncthreads();
    if (act) {
      float a0 = bias, a1 = 0.f, a2 = 0.f, a3 = 0.f;
      const uint4* vq = (const uint4*)sv32;
#pragma unroll
      for (int qq = 0; qq < 34; ++qq) {
        uint4 v = vq[qq];
        a0 = dot2(u2h2(v.x), u2h2(wr[qq * 4 + 0]), a0);
        a1 = dot2(u2h2(v.y), u2h2(wr[qq * 4 + 1]), a1);
        a2 = dot2(u2h2(v.z), u2h2(wr[qq * 4 + 2]), a2);
        a3 = dot2(u2h2(v.w), u2h2(wr[qq * 4 + 3]), a3);
      }
      float a = (a0 + a1) + (a2 + a3);
      a = (a > 0.f) ? a : 0.2f * a;
      float s = wave_sum(a * w2f) + b2f;
      if (l == 0) scores[e] = s;
      wmax = fmaxf(wmax, s);
    }
    __syncthreads();
  }
  if (l == 0) sRed[w] = wmax;
  __syncthreads();
  if (tid == 0)
    pmax[blockIdx.x] = fmaxf(fmaxf(sRed[0], sRed[1]), fmaxf(sRed[2], sRed[3]));
}

__global__ __launch_bounds__(256) void k_msg(
    const _Float16* __restrict__ h, const void* __restrict__ ei,
    const void* __restrict__ ea,
    const void* __restrict__ mw1, const void* __restrict__ mb1,
    const void* __restrict__ mw2, const void* __restrict__ mb2,
    const float* __restrict__ scores, const float* __restrict__ gmaxp,
    float* __restrict__ numer, float* __restrict__ denom,
    const int* __restrict__ flags, int lay) {
  const int fm = flags[0], im = flags[1];
  const int tid = threadIdx.x;
  const int slot = tid >> 7, t = tid & 127;
  __shared__ __align__(16) _Float16 sV[2][HID + EDGE_IN];
  __shared__ __align__(16) _Float16 sM1b[2][HID];
  unsigned int w1[72], w2[64];
  {
    const size_t b1p = (size_t)lay * HID * 72 + (size_t)t * 72;
#pragma unroll
    for (int i = 0; i < 72; ++i) w1[i] = load_pair(mw1, b1p + i, fm);
    const size_t b2p = (size_t)lay * HID * 64 + (size_t)t * 64;
#pragma unroll
    for (int i = 0; i < 64; ++i) w2[i] = load_pair(mw2, b2p + i, fm);
  }
  const float b1 = load_scal(mb1, lay * HID + t, fm);
  const float b2 = load_scal(mb2, lay * HID + t, fm);
  const float gmax = gmaxp[0];
  unsigned int* sv32 = (unsigned int*)sV[slot];
  for (int base = blockIdx.x * 2; base < N_EDGES; base += gridDim.x * 2) {
    const int e = base + slot;
    const int src = load_idx(ei, e, im);
    const int dst = load_idx(ei, N_EDGES + e, im);
    if (t < 64) {
      sv32[t] = ((const unsigned int*)(h + (size_t)src * HID))[t];
    } else if (t < 72) {
      sv32[t] = load_pair(ea, (size_t)e * 8 + (t - 64), fm);
    }
    __syncthreads();
    float a0 = b1, a1 = 0.f, a2 = 0.f, a3 = 0.f;
    const uint4* vq = (const uint4*)sv32;
#pragma unroll
    for (int qq = 0; qq < 18; ++qq) {
      uint4 v = vq[qq];
      a0 = dot2(u2h2(v.x), u2h2(w1[qq * 4 + 0]), a0);
      a1 = dot2(u2h2(v.y), u2h2(w1[qq * 4 + 1]), a1);
      a2 = dot2(u2h2(v.z), u2h2(w1[qq * 4 + 2]), a2);
      a3 = dot2(u2h2(v.w), u2h2(w1[qq * 4 + 3]), a3);
    }
    sM1b[slot][t] = (_Float16)fmaxf((a0 + a1) + (a2 + a3), 0.f);
    __syncthreads();
    float c0 = b2, c1 = 0.f, c2 = 0.f, c3 = 0.f;
    const uint4* mq = (const uint4*)sM1b[slot];
#pragma unroll
    for (int qq = 0; qq < 16; ++qq) {
      uint4 v = mq[qq];
      c0 = dot2(u2h2(v.x), u2h2(w2[qq * 4 + 0]), c0);
      c1 = dot2(u2h2(v.y), u2h2(w2[qq * 4 + 1]), c1);
      c2 = dot2(u2h2(v.z), u2h2(w2[qq * 4 + 2]), c2);
      c3 = dot2(u2h2(v.w), u2h2(w2[qq * 4 + 3]), c3);
    }
    float msg = (c0 + c1) + (c2 + c3);
    float wgt = __expf(scores[e] - gmax);
    atomicAdd(&numer[(size_t)dst * HID + t], msg * wgt);
    if (t == 0) atomicAdd(&denom[dst], wgt);
    __syncthreads();
  }
}

__global__ __launch_bounds__(256) void k_upd(
    _Float16* __restrict__ h, const float* __restrict__ numer,
    const float* __restrict__ denom,
    const void* __restrict__ uw1, const void* __restrict__ ub1,
    const void* __restrict__ uw2, const void* __restrict__ ub2,
    const void* __restrict__ lng, const void* __restrict__ lnb,
    const int* __restrict__ flags, int lay) {
  const int fm = flags[0];
  const int tid = threadIdx.x;
  const int slot = tid >> 7, t = tid & 127;
  const int wv = (tid >> 6) & 1;
  __shared__ __align__(16) _Float16 sV[2][2 * HID];
  __shared__ __align__(16) _Float16 sM1b[2][HID];
  __shared__ float sRed[2][2][2];
  unsigned int w1[128], w2[64];
  {
    const size_t b1p = (size_t)lay * HID * 128 + (size_t)t * 128;
#pragma unroll
    for (int i = 0; i < 128; ++i) w1[i] = load_pair(uw1, b1p + i, fm);
    const size_t b2p = (size_t)lay * HID * 64 + (size_t)t * 64;
#pragma unroll
    for (int i = 0; i < 64; ++i) w2[i] = load_pair(uw2, b2p + i, fm);
  }
  const float b1 = load_scal(ub1, lay * HID + t, fm);
  const float b2 = load_scal(ub2, lay * HID + t, fm);
  const float gg = load_scal(lng, lay * HID + t, fm);
  const float bb = load_scal(lnb, lay * HID + t, fm);
  unsigned int* sv32 = (unsigned int*)sV[slot];
  for (int base = blockIdx.x * 2; base < N_NODES; base += gridDim.x * 2) {
    const int n = base + slot;
    const float inv = 1.f / (denom[n] + 1e-6f);
    if (t < 64) {
      sv32[t] = ((const unsigned int*)(h + (size_t)n * HID))[t];
    } else {
      const int j = (t - 64) * 2;
      h2 p; p.x = (_Float16)(numer[(size_t)n * HID + j] * inv);
      p.y = (_Float16)(numer[(size_t)n * HID + j + 1] * inv);
      union { h2 hh; unsigned int u; } c; c.hh = p;
      sv32[64 + (t - 64)] = c.u;
    }
    __syncthreads();
    float a0 = b1, a1 = 0.f, a2 = 0.f, a3 = 0.f;
    const uint4* vq = (const uint4*)sv32;
#pragma unroll
    for (int qq = 0; qq < 32; ++qq) {
      uint4 v = vq[qq];
      a0 = dot2(u2h2(v.x), u2h2(w1[qq * 4 + 0]), a0);
      a1 = dot2(u2h2(v.y), u2h2(w1[qq * 4 + 1]), a1);
      a2 = dot2(u2h2(v.z), u2h2(w1[qq * 4 + 2]), a2);
      a3 = dot2(u2h2(v.w), u2h2(w1[qq * 4 + 3]), a3);
    }
    sM1b[slot][t] = (_Float16)fmaxf((a0 + a1) + (a2 + a3), 0.f);
    __syncthreads();
    float c0 = b2, c1 = 0.f, c2 = 0.f, c3 = 0.f;
    const uint4* mq = (const uint4*)sM1b[slot];
#pragma unroll
    for (int qq = 0; qq < 16; ++qq) {
      uint4 v = mq[qq];
      c0 = dot2(u2h2(v.x), u2h2(w2[qq * 4 + 0]), c0);
      c1 = dot2(u2h2(v.y), u2h2(w2[qq * 4 + 1]), c1);
      c2 = dot2(u2h2(v.z), u2h2(w2[qq * 4 + 2]), c2);
      c3 = dot2(u2h2(v.w), u2h2(w2[qq * 4 + 3]), c3);
    }
    const float hold = (float)((const _Float16*)sV[slot])[t];
    const float r = fmaxf((c0 + c1) + (c2 + c3) + hold, 0.f);
    float s1 = wave_sum(r);
    float s2 = wave_sum(r * r);
    if ((tid & 63) == 0) { sRed[slot][wv][0] = s1; sRed[slot][wv][1] = s2; }
    __syncthreads();
    const float S1 = sRed[slot][0][0] + sRed[slot][1][0];
    const float S2 = sRed[slot][0][1] + sRed[slot][1][1];
    const float mu = S1 * (1.f / HID);
    const float var = S2 * (1.f / HID) - mu * mu;
    const float rs = rsqrtf(var + 1e-5f);
    h[(size_t)n * HID + t] = (_Float16)((r - mu) * rs * gg + bb);
    __syncthreads();
  }
}

__global__ __launch_bounds__(256) void k_read(
    const _Float16* __restrict__ h, const void* __restrict__ gctx,
    const void* __restrict__ qw1, const void* __restrict__ qb1,
    const void* __restrict__ qw2, const void* __restrict__ qb2,
    void* __restrict__ out, const int* __restrict__ flags) {
  const int fm = flags[0];
  const int tid = threadIdx.x;
  const int slot = tid >> 7, t = tid & 127;
  const int wv = (tid >> 6) & 1;
  __shared__ __align__(16) _Float16 sV[2][HID];
  __shared__ __align__(16) _Float16 sCtx[GCTX];
  __shared__ float sRed[2][2];
  unsigned int w1[96];
#pragma unroll
  for (int i = 0; i < 96; ++i) w1[i] = load_pair(qw1, (size_t)t * 96 + i, fm);
  const float b1 = load_scal(qb1, t, fm);
  const float w2f = load_scal(qw2, t, fm);
  const float b2 = load_scal(qb2, 0, fm);
  if (tid < GCTX / 2)
    ((unsigned int*)sCtx)[tid] = load_pair(gctx, tid, fm);
  __syncthreads();
  unsigned int* sv32 = (unsigned int*)sV[slot];
  for (int base = blockIdx.x * 2; base < N_NODES; base += gridDim.x * 2) {
    const int n = base + slot;
    if (t < 64) sv32[t] = ((const unsigned int*)(h + (size_t)n * HID))[t];
    __syncthreads();
    float a0 = b1, a1 = 0.f, a2 = 0.f, a3 = 0.f;
    const uint4* vq = (const uint4*)sv32;
#pragma unroll
    for (int qq = 0; qq < 16; ++qq) {
      uint4 v = vq[qq];
      a0 = dot2(u2h2(v.x), u2h2(w1[qq * 4 + 0]), a0);
      a1 = dot2(u2h2(v.y), u2h2(w1[qq * 4 + 1]), a1);
      a2 = dot2(u2h2(v.z), u2h2(w1[qq * 4 + 2]), a2);
      a3 = dot2(u2h2(v.w), u2h2(w1[qq * 4 + 3]), a3);
    }
    const uint4* cq = (const uint4*)sCtx;
#pragma unroll
    for (int qq = 0; qq < 8; ++qq) {
      uint4 v = cq[qq];
      a0 = dot2(u2h2(v.x), u2h2(w1[64 + qq * 4 + 0]), a0);
      a1 = dot2(u2h2(v.y), u2h2(w1[64 + qq * 4 + 1]), a1);
      a2 = dot2(u2h2(v.z), u2h2(w1[64 + qq * 4 + 2]), a2);
      a3 = dot2(u2h2(v.w), u2h2(w1[64 + qq * 4 + 3]), a3);
    }
    float u = fmaxf((a0 + a1) + (a2 + a3), 0.f);
    float s = wave_sum(u * w2f);
    if ((tid & 63) == 0) sRed[slot][wv] = s;
    __syncthreads();
    if (t == 0) {
      const float val = sRed[slot][0] + sRed[slot][1] + b2;
      if (fm == 0) ((__hip_bfloat16*)out)[n] = __float2bfloat16(val);
      else if (fm == 2) ((_Float16*)out)[n] = (_Float16)val;
      else ((float*)out)[n] = val;
    }
    __syncthreads();
  }
}

extern "C" void kernel_launch(void* const* d_in, const int* in_sizes, int n_in,
                              void* d_out, int out_size, void* d_ws, size_t ws_size,
                              hipStream_t stream) {
  const void* x    = d_in[0];
  const void* ei   = d_in[1];
  const void* ea   = d_in[2];
  const void* gctx = d_in[3];
  const void* npw  = d_in[4];
  const void* npb  = d_in[5];
  const void* mw1  = d_in[6];
  const void* mb1  = d_in[7];
  const void* mw2  = d_in[8];
  const void* mb2  = d_in[9];
  const void* aw1  = d_in[10];
  const void* ab1  = d_in[11];
  const void* aw2  = d_in[12];
  const void* ab2  = d_in[13];
  const void* uw1  = d_in[14];
  const void* ub1  = d_in[15];
  const void* uw2  = d_in[16];
  const void* ub2  = d_in[17];
  const void* lng  = d_in[18];
  const void* lnb  = d_in[19];
  const void* qw1  = d_in[20];
  const void* qb1  = d_in[21];
  const void* qw2  = d_in[22];
  const void* qb2  = d_in[23];

  char* ws = (char*)d_ws;
  dim3 blk(256);

  size_t off = 0;
  auto alloc = [&](size_t bytes) {
    void* p = ws + off;
    off = (off + bytes + 255) & ~(size_t)255;
    return p;
  };
  int* flags       = (int*)alloc(8 * 4);
  _Float16* hbuf   = (_Float16*)alloc((size_t)N_NODES * HID * 2);
  float* scores    = (float*)alloc((size_t)N_EDGES * 4);
  float* pmax      = (float*)alloc(2048 * 4);
  float* gmax      = (float*)alloc(4);
  int* cnt         = (int*)alloc((size_t)N_NODES * 4);
  int* cur         = (int*)alloc((size_t)N_NODES * 4);
  int* row_ptr     = (int*)alloc((size_t)(N_NODES + 1) * 4);
  int* csum        = (int*)alloc(256 * 4);
  int2* sd2        = (int2*)alloc((size_t)N_EDGES * 8);
  _Float16* eaPerm = (_Float16*)alloc((size_t)N_EDGES * EDGE_IN * 2);
  _Float16* Sbuf   = (_Float16*)alloc((size_t)N_NODES * HID * 2);
  float* Dbuf      = (float*)alloc((size_t)N_NODES * 4);
  _Float16* msgbuf = (_Float16*)alloc((size_t)N_EDGES * HID * 2);
  const size_t need_big = off;

  if (ws_size >= need_big) {
    // ======== MFMA + CSR-ordered path ========
    k_detect<<<1, blk, 0, stream>>>((const unsigned int*)x, (const unsigned int*)ei, flags);
    k_proj<<<1024, blk, 0, stream>>>(x, npw, npb, hbuf, flags);
    hipMemsetAsync(cnt, 0, (size_t)N_NODES * 4, stream);
    k_hist<<<1024, blk, 0, stream>>>(ei, cnt, flags);
    k_psum<<<256, blk, 0, stream>>>(cnt, csum);
    k_fill<<<256, blk, 0, stream>>>(cnt, csum, row_ptr, cur);
    k_scatter<<<1024, blk, 0, stream>>>(ei, ea, cur, sd2, eaPerm, flags);
    for (int lay = 0; lay < NLAYER; ++lay) {
      k_edge<<<1024, blk, 0, stream>>>(hbuf, sd2, eaPerm, aw1, ab1, aw2, ab2,
                                       mw1, mb1, scores, pmax, msgbuf, flags, lay);
      k_rmax<<<1, blk, 0, stream>>>(pmax, 1024, gmax);
      k_gather<<<N_NODES / 16, blk, 0, stream>>>(msgbuf, scores, row_ptr, gmax,
                                                 Sbuf, Dbuf);
      k_upd3<<<1024, blk, 0, stream>>>(hbuf, Sbuf, Dbuf, mw2, mb2,
                                       uw1, ub1, uw2, ub2, lng, lnb, flags, lay);
    }
    k_read2<<<1024, blk, 0, stream>>>(hbuf, gctx, qw1, qb1, qw2, qb2, d_out, flags);
  } else {
    // ======== fallback: round-2 passing path ========
    size_t o2 = 0;
    int* flags2 = (int*)(ws + o2); o2 += 256;
    _Float16* hb = (_Float16*)(ws + o2); o2 += (size_t)N_NODES * HID * 2;
    o2 = (o2 + 255) & ~(size_t)255;
    float* sc = (float*)(ws + o2); o2 += (size_t)N_EDGES * 4;
    float* pm = (float*)(ws + o2); o2 += 1024 * 4;
    float* gm = (float*)(ws + o2); o2 += 256;
    float* numer = (float*)(ws + o2); o2 += (size_t)N_NODES * HID * 4;
    float* denom = (float*)(ws + o2); o2 += (size_t)N_NODES * 4;
    k_detect<<<1, blk, 0, stream>>>((const unsigned int*)x, (const unsigned int*)ei, flags2);
    k_proj<<<1024, blk, 0, stream>>>(x, npw, npb, hb, flags2);
    for (int lay = 0; lay < NLAYER; ++lay) {
      hipMemsetAsync(numer, 0, (size_t)N_NODES * HID * 4, stream);
      hipMemsetAsync(denom, 0, (size_t)N_NODES * 4, stream);
      k_attn<<<1024, blk, 0, stream>>>(hb, ei, ea, aw1, ab1, aw2, ab2, sc, pm,
                                       flags2, lay);
      k_rmax<<<1, blk, 0, stream>>>(pm, 1024, gm);
      k_msg<<<1024, blk, 0, stream>>>(hb, ei, ea, mw1, mb1, mw2, mb2, sc, gm,
                                      numer, denom, flags2, lay);
      k_upd<<<1024, blk, 0, stream>>>(hb, numer, denom, uw1, ub1, uw2, ub2, lng, lnb,
                                      flags2, lay);
    }
    k_read<<<1024, blk, 0, stream>>>(hb, gctx, qw1, qb1, qw2, qb2, d_out, flags2);
  }
}